// Round 5
// baseline (124.377 us; speedup 1.0000x reference)
//
#include <hip/hip_runtime.h>
#include <stdint.h>

// ============================ problem dims ============================
// hidden_states [4,2048,2048] f32, rows R=8192, H=2048, BD=N=VBD=256, top-8
// out = primary + sigmoid(top1) * gelu_lowrank(softmax_top8 @ gathered vals)
// Key restructure: down-proj is linear -> precompute PV = slot_values @ Wd^T
// (256x256) and gather from PV instead of materializing aux[8192][2048].

typedef float f32x4 __attribute__((ext_vector_type(4)));
typedef unsigned short u16x8 __attribute__((ext_vector_type(8)));
typedef unsigned short u16x4 __attribute__((ext_vector_type(4)));
typedef __bf16 bf16x8 __attribute__((ext_vector_type(8)));

// ============================ ws layout (bytes) ============================
#define WS_QW    0u          // u16 [256*2048]  q_proj_w bf16
#define WS_SK    1048576u    // u16 [256*256]   slot_keys bf16
#define WS_SV    1179648u    // u16 [256*2048]  slot_values bf16
#define WS_VDW   2228224u    // u16 [256*2048]  value_down_w bf16
#define WS_VUP   3276800u    // u16 [2048*256]  value_up_w bf16
#define WS_REL   4325376u    // f32 [256]       log(reliability)
#define WS_PV    4326400u    // f32 [256*256]   slot_values @ Wd^T
#define WS_GATE  4588544u    // f32 [8192]      sigmoid(top1)
#define WS_QP    4621312u    // f32 [2][8192][256] query split-K partials
#define WS_D     21398528u   // u16 [8192*256]  gelu(down) bf16
// total ~24.4 MB

static __device__ __forceinline__ unsigned short f2bf(float f) {
  union { float f; unsigned int u; } v; v.f = f;
  unsigned int r = v.u + 0x7FFFu + ((v.u >> 16) & 1u);
  return (unsigned short)(r >> 16);
}
static __device__ __forceinline__ bf16x8 as_bf16(u16x8 v) {
  return __builtin_bit_cast(bf16x8, v);
}
static __device__ __forceinline__ float gelu_tanh(float x) {
  float u = 0.7978845608028654f * (x + 0.044715f * x * x * x);
  return 0.5f * x * (1.0f + tanhf(u));
}

// ============================ K0: convert weights ============================
__global__ void k_prep(const float* __restrict__ qw, const float* __restrict__ sk,
                       const float* __restrict__ sv, const float* __restrict__ vdw,
                       const float* __restrict__ vup, const float* __restrict__ rel,
                       unsigned char* __restrict__ ws) {
  unsigned short* o_qw  = (unsigned short*)(ws + WS_QW);
  unsigned short* o_sk  = (unsigned short*)(ws + WS_SK);
  unsigned short* o_sv  = (unsigned short*)(ws + WS_SV);
  unsigned short* o_vdw = (unsigned short*)(ws + WS_VDW);
  unsigned short* o_vup = (unsigned short*)(ws + WS_VUP);
  float* o_rel = (float*)(ws + WS_REL);
  int tid = blockIdx.x * blockDim.x + threadIdx.x;
  int stride = gridDim.x * blockDim.x;
  for (int g = tid; g < 540736; g += stride) {
    const float* src; unsigned short* dst; int i;
    if      (g < 131072) { src = qw;  dst = o_qw;  i = g; }
    else if (g < 147456) { src = sk;  dst = o_sk;  i = g - 131072; }
    else if (g < 278528) { src = sv;  dst = o_sv;  i = g - 147456; }
    else if (g < 409600) { src = vdw; dst = o_vdw; i = g - 278528; }
    else if (g < 540672) { src = vup; dst = o_vup; i = g - 409600; }
    else {
      int i4 = (g - 540672) * 4;
      #pragma unroll
      for (int j = 0; j < 4; j++) o_rel[i4 + j] = logf(fmaxf(rel[i4 + j], 1e-10f));
      continue;
    }
    f32x4 v = *(const f32x4*)(src + (size_t)i * 4);
    u16x4 o;
    #pragma unroll
    for (int j = 0; j < 4; j++) o[j] = f2bf(v[j]);
    *(u16x4*)(dst + (size_t)i * 4) = o;
  }
}

// ============================ K_PV: PV = sv @ vdw^T ============================
// 64 blocks, each a 32x32 tile over K=2048. 4 waves, one 16x16 frag each.
__global__ __launch_bounds__(256, 2) void k_pv(unsigned char* __restrict__ ws) {
  const unsigned short* sv  = (const unsigned short*)(ws + WS_SV);
  const unsigned short* vdw = (const unsigned short*)(ws + WS_VDW);
  float* PV = (float*)(ws + WS_PV);
  __shared__ __align__(16) unsigned short As[32 * 64];
  __shared__ __align__(16) unsigned short Bs[32 * 64];
  int t = threadIdx.x, lane = t & 63, w = t >> 6;
  int nt = blockIdx.x >> 3, vt = blockIdx.x & 7;
  int mf = w >> 1, nf = w & 1;
  f32x4 acc = {0.f, 0.f, 0.f, 0.f};
  int r = t >> 3, c = t & 7;
  int sw8 = (c ^ (r & 7)) * 8;
  for (int k0 = 0; k0 < 2048; k0 += 64) {
    __syncthreads();
    *(u16x8*)&As[r * 64 + sw8] = *(const u16x8*)&sv[(size_t)(nt * 32 + r) * 2048 + k0 + c * 8];
    *(u16x8*)&Bs[r * 64 + sw8] = *(const u16x8*)&vdw[(size_t)(vt * 32 + r) * 2048 + k0 + c * 8];
    __syncthreads();
    #pragma unroll
    for (int kk = 0; kk < 2; kk++) {
      int ck = kk * 4 + (lane >> 4);
      int ar = mf * 16 + (lane & 15);
      int br = nf * 16 + (lane & 15);
      bf16x8 a = as_bf16(*(const u16x8*)&As[ar * 64 + ((ck ^ (ar & 7)) * 8)]);
      bf16x8 b = as_bf16(*(const u16x8*)&Bs[br * 64 + ((ck ^ (br & 7)) * 8)]);
      acc = __builtin_amdgcn_mfma_f32_16x16x32_bf16(a, b, acc, 0, 0, 0);
    }
  }
  int row = nt * 32 + mf * 16 + (lane >> 4) * 4;
  int col = vt * 32 + nf * 16 + (lane & 15);
  #pragma unroll
  for (int j = 0; j < 4; j++) PV[(row + j) * 256 + col] = acc[j];
}

// ============================ K1: query GEMM (split-K=2, pipelined) ============================
// qpart[ks][r][d] = hs[r, ks*1024 : +1024] @ qw^T.  BM=32, BN=256(all of BD).
// 512 blocks (256 row tiles x 2 k-slices) -> 4 blocks/CU.  Register-prefetch
// pipeline: issue tile t+1's global loads before the MFMA phase.
__global__ __launch_bounds__(256, 4) void k_query(const float* __restrict__ hs,
                                                  unsigned char* __restrict__ ws) {
  const unsigned short* qw = (const unsigned short*)(ws + WS_QW);
  float* qp = (float*)(ws + WS_QP);
  __shared__ __align__(16) unsigned short As[32 * 64];    // 4 KB
  __shared__ __align__(16) unsigned short Bs[256 * 64];   // 32 KB
  int t = threadIdx.x, lane = t & 63, w = t >> 6;
  int rt = blockIdx.x >> 1, ks = blockIdx.x & 1;
  int row0 = rt * 32, kbase = ks * 1024;
  f32x4 acc[2][4] = {};
  int sr = t >> 3, sc = t & 7;   // staging coords: 32 rows x 8 chunks of 8
  const float* aptr = hs + (size_t)(row0 + sr) * 2048 + kbase + sc * 8;
  const unsigned short* bptr = qw + (size_t)sr * 2048 + kbase + sc * 8;
  f32x4 pa0, pa1;
  u16x8 pb0, pb1, pb2, pb3, pb4, pb5, pb6, pb7;
  // prologue: tile 0 -> regs
  pa0 = *(const f32x4*)(aptr);
  pa1 = *(const f32x4*)(aptr + 4);
  pb0 = *(const u16x8*)(bptr + (size_t)0 * 32 * 2048);
  pb1 = *(const u16x8*)(bptr + (size_t)1 * 32 * 2048);
  pb2 = *(const u16x8*)(bptr + (size_t)2 * 32 * 2048);
  pb3 = *(const u16x8*)(bptr + (size_t)3 * 32 * 2048);
  pb4 = *(const u16x8*)(bptr + (size_t)4 * 32 * 2048);
  pb5 = *(const u16x8*)(bptr + (size_t)5 * 32 * 2048);
  pb6 = *(const u16x8*)(bptr + (size_t)6 * 32 * 2048);
  pb7 = *(const u16x8*)(bptr + (size_t)7 * 32 * 2048);
  for (int kt = 0; kt < 16; kt++) {
    __syncthreads();   // previous tile's LDS readers done
    {  // stage regs -> LDS (A: fp32->bf16)
      u16x8 o;
      #pragma unroll
      for (int j = 0; j < 4; j++) { o[j] = f2bf(pa0[j]); o[4 + j] = f2bf(pa1[j]); }
      *(u16x8*)&As[sr * 64 + ((sc ^ (sr & 7)) * 8)] = o;
      u16x8 pb[8] = {pb0, pb1, pb2, pb3, pb4, pb5, pb6, pb7};
      #pragma unroll
      for (int i = 0; i < 8; i++) {
        int n = i * 32 + sr;
        *(u16x8*)&Bs[n * 64 + ((sc ^ (n & 7)) * 8)] = pb[i];
      }
    }
    __syncthreads();
    if (kt < 15) {  // prefetch tile kt+1 into regs (overlaps MFMA below)
      int off = (kt + 1) * 64;
      pa0 = *(const f32x4*)(aptr + off);
      pa1 = *(const f32x4*)(aptr + off + 4);
      pb0 = *(const u16x8*)(bptr + (size_t)0 * 32 * 2048 + off);
      pb1 = *(const u16x8*)(bptr + (size_t)1 * 32 * 2048 + off);
      pb2 = *(const u16x8*)(bptr + (size_t)2 * 32 * 2048 + off);
      pb3 = *(const u16x8*)(bptr + (size_t)3 * 32 * 2048 + off);
      pb4 = *(const u16x8*)(bptr + (size_t)4 * 32 * 2048 + off);
      pb5 = *(const u16x8*)(bptr + (size_t)5 * 32 * 2048 + off);
      pb6 = *(const u16x8*)(bptr + (size_t)6 * 32 * 2048 + off);
      pb7 = *(const u16x8*)(bptr + (size_t)7 * 32 * 2048 + off);
    }
    #pragma unroll
    for (int kk = 0; kk < 2; kk++) {
      int ck = kk * 4 + (lane >> 4);
      bf16x8 a[2], b[4];
      #pragma unroll
      for (int mf = 0; mf < 2; mf++) {
        int arow = mf * 16 + (lane & 15);
        a[mf] = as_bf16(*(const u16x8*)&As[arow * 64 + ((ck ^ (arow & 7)) * 8)]);
      }
      #pragma unroll
      for (int nf = 0; nf < 4; nf++) {
        int brow = w * 64 + nf * 16 + (lane & 15);
        b[nf] = as_bf16(*(const u16x8*)&Bs[brow * 64 + ((ck ^ (brow & 7)) * 8)]);
      }
      #pragma unroll
      for (int mf = 0; mf < 2; mf++)
        #pragma unroll
        for (int nf = 0; nf < 4; nf++)
          acc[mf][nf] = __builtin_amdgcn_mfma_f32_16x16x32_bf16(a[mf], b[nf], acc[mf][nf], 0, 0, 0);
    }
  }
  float* outp = qp + (size_t)ks * 8192 * 256;
  #pragma unroll
  for (int mf = 0; mf < 2; mf++) {
    int row = row0 + mf * 16 + (lane >> 4) * 4;
    #pragma unroll
    for (int nf = 0; nf < 4; nf++) {
      int col = w * 64 + nf * 16 + (lane & 15);
      #pragma unroll
      for (int j = 0; j < 4; j++) outp[(size_t)(row + j) * 256 + col] = acc[mf][nf][j];
    }
  }
}

// ============================ K2: scores + wave-parallel top8 + PV gather ============================
// 512 blocks x 16 rows. Phase 1: Q=qp0+qp1 -> bf16 LDS. Phase 2: MFMA scores
// -> Ss (stride 260 f32, per-row reads contiguous). Phase 3: one WAVE per row:
// pack (ordered-score|255-idx) u32, 8x {max4 + 6-step shfl_xor butterfly max,
// owner masks winner}; all lanes decode winners redundantly (no LDS, no
// divergence), softmax + gate, coalesced f32x4 PV gather, gelu -> D bf16.
#define QSTR 264   // ushort stride
#define SSTR 260   // f32 stride: 1040B row -> 16B aligned, contiguous reads
__global__ __launch_bounds__(256, 4) void k_score(unsigned char* __restrict__ ws) {
  const float* qp = (const float*)(ws + WS_QP);
  const unsigned short* sk = (const unsigned short*)(ws + WS_SK);
  const float* relm = (const float*)(ws + WS_REL);
  const float* PV = (const float*)(ws + WS_PV);
  float* gates = (float*)(ws + WS_GATE);
  unsigned short* D = (unsigned short*)(ws + WS_D);
  __shared__ __align__(16) unsigned short Qs[16 * QSTR];
  __shared__ __align__(16) float Ss[16 * SSTR];
  int t = threadIdx.x, lane = t & 63, w = t >> 6;
  int row0 = blockIdx.x * 16;
  // phase 1: query = qpart0 + qpart1 -> bf16 -> LDS (16 rows x 256 cols)
  #pragma unroll
  for (int i = 0; i < 4; i++) {
    int id = i * 256 + t, r = id >> 6, c4 = id & 63;
    const float* p0 = qp + (size_t)(row0 + r) * 256 + c4 * 4;
    f32x4 a = *(const f32x4*)p0;
    f32x4 b = *(const f32x4*)(p0 + 8192 * 256);
    u16x4 o;
    #pragma unroll
    for (int j = 0; j < 4; j++) o[j] = f2bf(a[j] + b[j]);
    *(u16x4*)&Qs[r * QSTR + c4 * 4] = o;
  }
  __syncthreads();
  // phase 2: scores[16][256] = Q @ sk^T / 16 + rel_mask
  {
    f32x4 acc[4] = {};
    for (int ksb = 0; ksb < 8; ksb++) {
      int ck = lane >> 4;
      bf16x8 a = as_bf16(*(const u16x8*)&Qs[(lane & 15) * QSTR + ksb * 32 + ck * 8]);
      #pragma unroll
      for (int nf = 0; nf < 4; nf++) {
        int n = w * 64 + nf * 16 + (lane & 15);
        bf16x8 b = as_bf16(*(const u16x8*)&sk[(size_t)n * 256 + ksb * 32 + ck * 8]);
        acc[nf] = __builtin_amdgcn_mfma_f32_16x16x32_bf16(a, b, acc[nf], 0, 0, 0);
      }
    }
    #pragma unroll
    for (int nf = 0; nf < 4; nf++) {
      int n = w * 64 + nf * 16 + (lane & 15);
      float rm = relm[n];
      int rr = (lane >> 4) * 4;
      #pragma unroll
      for (int j = 0; j < 4; j++) Ss[(rr + j) * SSTR + n] = acc[nf][j] * 0.0625f + rm;
    }
  }
  __syncthreads();
  // phase 3: wave w handles rows w*4 .. w*4+3
  for (int rr = 0; rr < 4; rr++) {
    int row = w * 4 + rr;
    f32x4 sv4 = *(const f32x4*)&Ss[row * SSTR + lane * 4];
    unsigned int key[4];
    #pragma unroll
    for (int j = 0; j < 4; j++) {
      unsigned int u = __builtin_bit_cast(unsigned int, sv4[j]);
      unsigned int os = (u & 0x80000000u) ? ~u : (u | 0x80000000u);
      key[j] = (os & 0xFFFFFF00u) | (unsigned int)(255 - (lane * 4 + j));
    }
    unsigned int win[8];
    #pragma unroll
    for (int e = 0; e < 8; e++) {
      unsigned int m01 = key[0] > key[1] ? key[0] : key[1];
      unsigned int m23 = key[2] > key[3] ? key[2] : key[3];
      unsigned int m = m01 > m23 ? m01 : m23;
      #pragma unroll
      for (int d = 1; d < 64; d <<= 1) {
        unsigned int o = (unsigned int)__shfl_xor((int)m, d, 64);
        m = o > m ? o : m;
      }
      win[e] = m;
      #pragma unroll
      for (int j = 0; j < 4; j++) if (key[j] == m) key[j] = 0u;
    }
    // decode (all lanes redundantly)
    float s8[8]; int i8[8];
    #pragma unroll
    for (int e = 0; e < 8; e++) {
      i8[e] = 255 - (int)(win[e] & 0xFFu);
      unsigned int os = win[e] & 0xFFFFFF00u;
      unsigned int u = (os & 0x80000000u) ? (os ^ 0x80000000u) : ~os;
      s8[e] = __builtin_bit_cast(float, u);
    }
    float m0 = s8[0], sum = 0.f, we[8];
    #pragma unroll
    for (int e = 0; e < 8; e++) { we[e] = expf(s8[e] - m0); sum += we[e]; }
    float inv = 1.f / sum;
    // PV gather: lane l owns cols 4l..4l+3 (f32x4, contiguous 1KB per slot)
    f32x4 accv = {0.f, 0.f, 0.f, 0.f};
    #pragma unroll
    for (int e = 0; e < 8; e++) {
      float wk = we[e] * inv;
      f32x4 p = *(const f32x4*)(PV + (size_t)i8[e] * 256 + lane * 4);
      #pragma unroll
      for (int j = 0; j < 4; j++) accv[j] += wk * p[j];
    }
    u16x4 o;
    #pragma unroll
    for (int j = 0; j < 4; j++) o[j] = f2bf(gelu_tanh(accv[j]));
    *(u16x4*)&D[(size_t)(row0 + row) * 256 + lane * 4] = o;
    if (lane == 0) gates[row0 + row] = 1.f / (1.f + expf(-m0));
  }
}

// ============================ K3: up-GEMM + epilogue ============================
// out[r,h] = primary[r,h] + gate[r] * (D[r,:] @ vup[h,:])   K=256
// 1024 blocks (64 row x 16 col tiles), XCD-chunk swizzle, 4 waves 2x2.
// primary tile is PREFETCHED into registers (16 x f32x4) at kernel start so
// its HBM/L3 latency hides under the whole GEMM; epilogue has no global-load
// waits.  Acc is restaged through LDS (union with As/Bs) for coalesced f32x4
// stores.
union KOutLds {
  unsigned short AB[2][128 * 64];  // As = AB[0], Bs = AB[1]  (32 KB)
  float stage[32 * 132];           // 16.5 KB, inside AB footprint
};
__global__ __launch_bounds__(256, 4) void k_out(const float* __restrict__ primary,
                                                float* __restrict__ out,
                                                unsigned char* __restrict__ ws) {
  const unsigned short* D = (const unsigned short*)(ws + WS_D);
  const unsigned short* vup = (const unsigned short*)(ws + WS_VUP);
  const float* gates = (const float*)(ws + WS_GATE);
  __shared__ __align__(16) KOutLds u;
  __shared__ float gate_s[128];
  unsigned short* As = u.AB[0];
  unsigned short* Bs = u.AB[1];
  int t = threadIdx.x, lane = t & 63, w = t >> 6;
  int bid = blockIdx.x;
  int L = (bid & 7) * 128 + (bid >> 3);   // bijective: 1024 % 8 == 0
  int rt = L >> 4, ct = L & 15;
  int wm = w >> 1, wn = w & 1;
  // ---- prefetch primary tile into registers (latency hides under GEMM) ----
  f32x4 pref[4][4];
  {
    int r = t >> 5, c4 = t & 31;                 // r in [0,8), per i adds 8
    const float* pbase = primary + (size_t)(rt * 128 + r) * 2048 + ct * 128 + c4 * 4;
    #pragma unroll
    for (int c = 0; c < 4; c++)
      #pragma unroll
      for (int i = 0; i < 4; i++)
        pref[c][i] = *(const f32x4*)(pbase + (size_t)(c * 32 + i * 8) * 2048);
  }
  if (t < 128) gate_s[t] = gates[rt * 128 + t];
  f32x4 acc[4][4] = {};
  for (int k0 = 0; k0 < 256; k0 += 64) {
    __syncthreads();
    #pragma unroll
    for (int i = 0; i < 4; i++) {
      int id = i * 256 + t, r = id >> 3, c = id & 7;
      int sw8 = (c ^ (r & 7)) * 8;
      *(u16x8*)&As[r * 64 + sw8] = *(const u16x8*)&D[(size_t)(rt * 128 + r) * 256 + k0 + c * 8];
      *(u16x8*)&Bs[r * 64 + sw8] = *(const u16x8*)&vup[(size_t)(ct * 128 + r) * 256 + k0 + c * 8];
    }
    __syncthreads();
    #pragma unroll
    for (int kk = 0; kk < 2; kk++) {
      int ck = kk * 4 + (lane >> 4);
      bf16x8 a[4], b[4];
      #pragma unroll
      for (int mf = 0; mf < 4; mf++) {
        int ar = wm * 64 + mf * 16 + (lane & 15);
        a[mf] = as_bf16(*(const u16x8*)&As[ar * 64 + ((ck ^ (ar & 7)) * 8)]);
      }
      #pragma unroll
      for (int nf = 0; nf < 4; nf++) {
        int br = wn * 64 + nf * 16 + (lane & 15);
        b[nf] = as_bf16(*(const u16x8*)&Bs[br * 64 + ((ck ^ (br & 7)) * 8)]);
      }
      #pragma unroll
      for (int mf = 0; mf < 4; mf++)
        #pragma unroll
        for (int nf = 0; nf < 4; nf++)
          acc[mf][nf] = __builtin_amdgcn_mfma_f32_16x16x32_bf16(a[mf], b[nf], acc[mf][nf], 0, 0, 0);
    }
  }
  // ---- coalesced epilogue: 4 chunks of 32 rows x 128 cols, no global waits ----
  #pragma unroll
  for (int c = 0; c < 4; c++) {
    __syncthreads();   // prior readers of LDS done
    if (wm == (c >> 1)) {
      #pragma unroll
      for (int mi = 0; mi < 2; mi++) {
        int mf = (c & 1) * 2 + mi;
        #pragma unroll
        for (int nf = 0; nf < 4; nf++) {
          int col = wn * 64 + nf * 16 + (lane & 15);
          #pragma unroll
          for (int j = 0; j < 4; j++) {
            int r = mi * 16 + (lane >> 4) * 4 + j;
            u.stage[r * 132 + col] = acc[mf][nf][j];
          }
        }
      }
    }
    __syncthreads();
    #pragma unroll
    for (int i = 0; i < 4; i++) {
      int idx = i * 256 + t, r = idx >> 5, c4 = idx & 31;
      int row = rt * 128 + c * 32 + r;
      size_t o = (size_t)row * 2048 + ct * 128 + c4 * 4;
      f32x4 p = pref[c][i];
      f32x4 s = *(const f32x4*)&u.stage[r * 132 + c4 * 4];
      float g = gate_s[c * 32 + r];
      f32x4 ov;
      #pragma unroll
      for (int j = 0; j < 4; j++) ov[j] = p[j] + g * s[j];
      *(f32x4*)(out + o) = ov;
    }
  }
}

// ============================ launch ============================
extern "C" void kernel_launch(void* const* d_in, const int* in_sizes, int n_in,
                              void* d_out, int out_size, void* d_ws, size_t ws_size,
                              hipStream_t stream) {
  const float* hs      = (const float*)d_in[0];
  const float* primary = (const float*)d_in[1];
  const float* qw      = (const float*)d_in[2];
  const float* sk      = (const float*)d_in[3];
  const float* sv      = (const float*)d_in[4];
  const float* rel     = (const float*)d_in[5];
  const float* vdw     = (const float*)d_in[6];
  const float* vup     = (const float*)d_in[7];
  unsigned char* ws = (unsigned char*)d_ws;
  float* out = (float*)d_out;

  k_prep<<<dim3(256), dim3(256), 0, stream>>>(qw, sk, sv, vdw, vup, rel, ws);
  k_pv<<<dim3(64), dim3(256), 0, stream>>>(ws);
  k_query<<<dim3(512), dim3(256), 0, stream>>>(hs, ws);
  k_score<<<dim3(512), dim3(256), 0, stream>>>(ws);
  k_out<<<dim3(1024), dim3(256), 0, stream>>>(primary, out, ws);
}

// Round 6
// 108.917 us; speedup vs baseline: 1.1419x; 1.1419x over previous
//
#include <hip/hip_runtime.h>
#include <stdint.h>

// ============================ problem dims ============================
// hidden_states [4,2048,2048] f32, rows R=8192, H=2048, BD=N=VBD=256, top-8
// out = primary + sigmoid(top1) * gelu_lowrank(softmax_top8 @ gathered vals)
// Key restructure: down-proj is linear -> precompute PV = slot_values @ Wd^T
// (256x256) and gather from PV instead of materializing aux[8192][2048].

typedef float f32x4 __attribute__((ext_vector_type(4)));
typedef unsigned short u16x8 __attribute__((ext_vector_type(8)));
typedef unsigned short u16x4 __attribute__((ext_vector_type(4)));
typedef __bf16 bf16x8 __attribute__((ext_vector_type(8)));

// ============================ ws layout (bytes) ============================
#define WS_QW    0u          // u16 [256*2048]  q_proj_w bf16
#define WS_SK    1048576u    // u16 [256*256]   slot_keys bf16
#define WS_SV    1179648u    // u16 [256*2048]  slot_values bf16
#define WS_VDW   2228224u    // u16 [256*2048]  value_down_w bf16
#define WS_VUP   3276800u    // u16 [2048*256]  value_up_w bf16
#define WS_REL   4325376u    // f32 [256]       log(reliability)
#define WS_PV    4326400u    // f32 [256*256]   slot_values @ Wd^T
#define WS_GATE  4588544u    // f32 [8192]      sigmoid(top1)
#define WS_QP    4621312u    // f32 [2][8192][256] query split-K partials
#define WS_D     21398528u   // u16 [8192*256]  gelu(down) bf16
// total ~24.4 MB

static __device__ __forceinline__ unsigned short f2bf(float f) {
  union { float f; unsigned int u; } v; v.f = f;
  unsigned int r = v.u + 0x7FFFu + ((v.u >> 16) & 1u);
  return (unsigned short)(r >> 16);
}
static __device__ __forceinline__ bf16x8 as_bf16(u16x8 v) {
  return __builtin_bit_cast(bf16x8, v);
}
static __device__ __forceinline__ float gelu_tanh(float x) {
  float u = 0.7978845608028654f * (x + 0.044715f * x * x * x);
  return 0.5f * x * (1.0f + tanhf(u));
}

// ============================ K0: convert weights ============================
__global__ void k_prep(const float* __restrict__ qw, const float* __restrict__ sk,
                       const float* __restrict__ sv, const float* __restrict__ vdw,
                       const float* __restrict__ vup, const float* __restrict__ rel,
                       unsigned char* __restrict__ ws) {
  unsigned short* o_qw  = (unsigned short*)(ws + WS_QW);
  unsigned short* o_sk  = (unsigned short*)(ws + WS_SK);
  unsigned short* o_sv  = (unsigned short*)(ws + WS_SV);
  unsigned short* o_vdw = (unsigned short*)(ws + WS_VDW);
  unsigned short* o_vup = (unsigned short*)(ws + WS_VUP);
  float* o_rel = (float*)(ws + WS_REL);
  int tid = blockIdx.x * blockDim.x + threadIdx.x;
  int stride = gridDim.x * blockDim.x;
  for (int g = tid; g < 540736; g += stride) {
    const float* src; unsigned short* dst; int i;
    if      (g < 131072) { src = qw;  dst = o_qw;  i = g; }
    else if (g < 147456) { src = sk;  dst = o_sk;  i = g - 131072; }
    else if (g < 278528) { src = sv;  dst = o_sv;  i = g - 147456; }
    else if (g < 409600) { src = vdw; dst = o_vdw; i = g - 278528; }
    else if (g < 540672) { src = vup; dst = o_vup; i = g - 409600; }
    else {
      int i4 = (g - 540672) * 4;
      #pragma unroll
      for (int j = 0; j < 4; j++) o_rel[i4 + j] = logf(fmaxf(rel[i4 + j], 1e-10f));
      continue;
    }
    f32x4 v = *(const f32x4*)(src + (size_t)i * 4);
    u16x4 o;
    #pragma unroll
    for (int j = 0; j < 4; j++) o[j] = f2bf(v[j]);
    *(u16x4*)(dst + (size_t)i * 4) = o;
  }
}

// ============================ K_PV: PV = sv @ vdw^T ============================
// 64 blocks, each a 32x32 tile over K=2048. 4 waves, one 16x16 frag each.
__global__ __launch_bounds__(256, 2) void k_pv(unsigned char* __restrict__ ws) {
  const unsigned short* sv  = (const unsigned short*)(ws + WS_SV);
  const unsigned short* vdw = (const unsigned short*)(ws + WS_VDW);
  float* PV = (float*)(ws + WS_PV);
  __shared__ __align__(16) unsigned short As[32 * 64];
  __shared__ __align__(16) unsigned short Bs[32 * 64];
  int t = threadIdx.x, lane = t & 63, w = t >> 6;
  int nt = blockIdx.x >> 3, vt = blockIdx.x & 7;
  int mf = w >> 1, nf = w & 1;
  f32x4 acc = {0.f, 0.f, 0.f, 0.f};
  int r = t >> 3, c = t & 7;
  int sw8 = (c ^ (r & 7)) * 8;
  for (int k0 = 0; k0 < 2048; k0 += 64) {
    __syncthreads();
    *(u16x8*)&As[r * 64 + sw8] = *(const u16x8*)&sv[(size_t)(nt * 32 + r) * 2048 + k0 + c * 8];
    *(u16x8*)&Bs[r * 64 + sw8] = *(const u16x8*)&vdw[(size_t)(vt * 32 + r) * 2048 + k0 + c * 8];
    __syncthreads();
    #pragma unroll
    for (int kk = 0; kk < 2; kk++) {
      int ck = kk * 4 + (lane >> 4);
      int ar = mf * 16 + (lane & 15);
      int br = nf * 16 + (lane & 15);
      bf16x8 a = as_bf16(*(const u16x8*)&As[ar * 64 + ((ck ^ (ar & 7)) * 8)]);
      bf16x8 b = as_bf16(*(const u16x8*)&Bs[br * 64 + ((ck ^ (br & 7)) * 8)]);
      acc = __builtin_amdgcn_mfma_f32_16x16x32_bf16(a, b, acc, 0, 0, 0);
    }
  }
  int row = nt * 32 + mf * 16 + (lane >> 4) * 4;
  int col = vt * 32 + nf * 16 + (lane & 15);
  #pragma unroll
  for (int j = 0; j < 4; j++) PV[(row + j) * 256 + col] = acc[j];
}

// ============================ K1: query GEMM (split-K=2, pipelined) ============================
// qpart[ks][r][d] = hs[r, ks*1024 : +1024] @ qw^T.  BM=32, BN=256(all of BD).
// 512 blocks (256 row tiles x 2 k-slices) -> 4 blocks/CU.  Register-prefetch
// pipeline: issue tile t+1's global loads before the MFMA phase.
__global__ __launch_bounds__(256, 4) void k_query(const float* __restrict__ hs,
                                                  unsigned char* __restrict__ ws) {
  const unsigned short* qw = (const unsigned short*)(ws + WS_QW);
  float* qp = (float*)(ws + WS_QP);
  __shared__ __align__(16) unsigned short As[32 * 64];    // 4 KB
  __shared__ __align__(16) unsigned short Bs[256 * 64];   // 32 KB
  int t = threadIdx.x, lane = t & 63, w = t >> 6;
  int rt = blockIdx.x >> 1, ks = blockIdx.x & 1;
  int row0 = rt * 32, kbase = ks * 1024;
  f32x4 acc[2][4] = {};
  int sr = t >> 3, sc = t & 7;   // staging coords: 32 rows x 8 chunks of 8
  const float* aptr = hs + (size_t)(row0 + sr) * 2048 + kbase + sc * 8;
  const unsigned short* bptr = qw + (size_t)sr * 2048 + kbase + sc * 8;
  f32x4 pa0, pa1;
  u16x8 pb0, pb1, pb2, pb3, pb4, pb5, pb6, pb7;
  // prologue: tile 0 -> regs
  pa0 = *(const f32x4*)(aptr);
  pa1 = *(const f32x4*)(aptr + 4);
  pb0 = *(const u16x8*)(bptr + (size_t)0 * 32 * 2048);
  pb1 = *(const u16x8*)(bptr + (size_t)1 * 32 * 2048);
  pb2 = *(const u16x8*)(bptr + (size_t)2 * 32 * 2048);
  pb3 = *(const u16x8*)(bptr + (size_t)3 * 32 * 2048);
  pb4 = *(const u16x8*)(bptr + (size_t)4 * 32 * 2048);
  pb5 = *(const u16x8*)(bptr + (size_t)5 * 32 * 2048);
  pb6 = *(const u16x8*)(bptr + (size_t)6 * 32 * 2048);
  pb7 = *(const u16x8*)(bptr + (size_t)7 * 32 * 2048);
  for (int kt = 0; kt < 16; kt++) {
    __syncthreads();   // previous tile's LDS readers done
    {  // stage regs -> LDS (A: fp32->bf16)
      u16x8 o;
      #pragma unroll
      for (int j = 0; j < 4; j++) { o[j] = f2bf(pa0[j]); o[4 + j] = f2bf(pa1[j]); }
      *(u16x8*)&As[sr * 64 + ((sc ^ (sr & 7)) * 8)] = o;
      u16x8 pb[8] = {pb0, pb1, pb2, pb3, pb4, pb5, pb6, pb7};
      #pragma unroll
      for (int i = 0; i < 8; i++) {
        int n = i * 32 + sr;
        *(u16x8*)&Bs[n * 64 + ((sc ^ (n & 7)) * 8)] = pb[i];
      }
    }
    __syncthreads();
    if (kt < 15) {  // prefetch tile kt+1 into regs (overlaps MFMA below)
      int off = (kt + 1) * 64;
      pa0 = *(const f32x4*)(aptr + off);
      pa1 = *(const f32x4*)(aptr + off + 4);
      pb0 = *(const u16x8*)(bptr + (size_t)0 * 32 * 2048 + off);
      pb1 = *(const u16x8*)(bptr + (size_t)1 * 32 * 2048 + off);
      pb2 = *(const u16x8*)(bptr + (size_t)2 * 32 * 2048 + off);
      pb3 = *(const u16x8*)(bptr + (size_t)3 * 32 * 2048 + off);
      pb4 = *(const u16x8*)(bptr + (size_t)4 * 32 * 2048 + off);
      pb5 = *(const u16x8*)(bptr + (size_t)5 * 32 * 2048 + off);
      pb6 = *(const u16x8*)(bptr + (size_t)6 * 32 * 2048 + off);
      pb7 = *(const u16x8*)(bptr + (size_t)7 * 32 * 2048 + off);
    }
    #pragma unroll
    for (int kk = 0; kk < 2; kk++) {
      int ck = kk * 4 + (lane >> 4);
      bf16x8 a[2], b[4];
      #pragma unroll
      for (int mf = 0; mf < 2; mf++) {
        int arow = mf * 16 + (lane & 15);
        a[mf] = as_bf16(*(const u16x8*)&As[arow * 64 + ((ck ^ (arow & 7)) * 8)]);
      }
      #pragma unroll
      for (int nf = 0; nf < 4; nf++) {
        int brow = w * 64 + nf * 16 + (lane & 15);
        b[nf] = as_bf16(*(const u16x8*)&Bs[brow * 64 + ((ck ^ (brow & 7)) * 8)]);
      }
      #pragma unroll
      for (int mf = 0; mf < 2; mf++)
        #pragma unroll
        for (int nf = 0; nf < 4; nf++)
          acc[mf][nf] = __builtin_amdgcn_mfma_f32_16x16x32_bf16(a[mf], b[nf], acc[mf][nf], 0, 0, 0);
    }
  }
  float* outp = qp + (size_t)ks * 8192 * 256;
  #pragma unroll
  for (int mf = 0; mf < 2; mf++) {
    int row = row0 + mf * 16 + (lane >> 4) * 4;
    #pragma unroll
    for (int nf = 0; nf < 4; nf++) {
      int col = w * 64 + nf * 16 + (lane & 15);
      #pragma unroll
      for (int j = 0; j < 4; j++) outp[(size_t)(row + j) * 256 + col] = acc[mf][nf][j];
    }
  }
}

// ============================ K2: scores + wave-parallel top8 + PV gather ============================
// 512 blocks x 16 rows. Phase 1: Q=qp0+qp1 -> bf16 LDS. Phase 2: MFMA scores
// -> Ss (stride 260 f32, per-row reads contiguous). Phase 3: one WAVE per row:
// pack (ordered-score|255-idx) u32, 8x {max4 + 6-step shfl_xor butterfly max,
// owner masks winner}; all lanes decode winners redundantly (no LDS, no
// divergence), softmax + gate, coalesced f32x4 PV gather, gelu -> D bf16.
#define QSTR 264   // ushort stride
#define SSTR 260   // f32 stride: 1040B row -> 16B aligned, contiguous reads
__global__ __launch_bounds__(256, 4) void k_score(unsigned char* __restrict__ ws) {
  const float* qp = (const float*)(ws + WS_QP);
  const unsigned short* sk = (const unsigned short*)(ws + WS_SK);
  const float* relm = (const float*)(ws + WS_REL);
  const float* PV = (const float*)(ws + WS_PV);
  float* gates = (float*)(ws + WS_GATE);
  unsigned short* D = (unsigned short*)(ws + WS_D);
  __shared__ __align__(16) unsigned short Qs[16 * QSTR];
  __shared__ __align__(16) float Ss[16 * SSTR];
  int t = threadIdx.x, lane = t & 63, w = t >> 6;
  int row0 = blockIdx.x * 16;
  // phase 1: query = qpart0 + qpart1 -> bf16 -> LDS (16 rows x 256 cols)
  #pragma unroll
  for (int i = 0; i < 4; i++) {
    int id = i * 256 + t, r = id >> 6, c4 = id & 63;
    const float* p0 = qp + (size_t)(row0 + r) * 256 + c4 * 4;
    f32x4 a = *(const f32x4*)p0;
    f32x4 b = *(const f32x4*)(p0 + 8192 * 256);
    u16x4 o;
    #pragma unroll
    for (int j = 0; j < 4; j++) o[j] = f2bf(a[j] + b[j]);
    *(u16x4*)&Qs[r * QSTR + c4 * 4] = o;
  }
  __syncthreads();
  // phase 2: scores[16][256] = Q @ sk^T / 16 + rel_mask
  {
    f32x4 acc[4] = {};
    for (int ksb = 0; ksb < 8; ksb++) {
      int ck = lane >> 4;
      bf16x8 a = as_bf16(*(const u16x8*)&Qs[(lane & 15) * QSTR + ksb * 32 + ck * 8]);
      #pragma unroll
      for (int nf = 0; nf < 4; nf++) {
        int n = w * 64 + nf * 16 + (lane & 15);
        bf16x8 b = as_bf16(*(const u16x8*)&sk[(size_t)n * 256 + ksb * 32 + ck * 8]);
        acc[nf] = __builtin_amdgcn_mfma_f32_16x16x32_bf16(a, b, acc[nf], 0, 0, 0);
      }
    }
    #pragma unroll
    for (int nf = 0; nf < 4; nf++) {
      int n = w * 64 + nf * 16 + (lane & 15);
      float rm = relm[n];
      int rr = (lane >> 4) * 4;
      #pragma unroll
      for (int j = 0; j < 4; j++) Ss[(rr + j) * SSTR + n] = acc[nf][j] * 0.0625f + rm;
    }
  }
  __syncthreads();
  // phase 3: wave w handles rows w*4 .. w*4+3
  for (int rr = 0; rr < 4; rr++) {
    int row = w * 4 + rr;
    f32x4 sv4 = *(const f32x4*)&Ss[row * SSTR + lane * 4];
    unsigned int key[4];
    #pragma unroll
    for (int j = 0; j < 4; j++) {
      unsigned int u = __builtin_bit_cast(unsigned int, sv4[j]);
      unsigned int os = (u & 0x80000000u) ? ~u : (u | 0x80000000u);
      key[j] = (os & 0xFFFFFF00u) | (unsigned int)(255 - (lane * 4 + j));
    }
    unsigned int win[8];
    #pragma unroll
    for (int e = 0; e < 8; e++) {
      unsigned int m01 = key[0] > key[1] ? key[0] : key[1];
      unsigned int m23 = key[2] > key[3] ? key[2] : key[3];
      unsigned int m = m01 > m23 ? m01 : m23;
      #pragma unroll
      for (int d = 1; d < 64; d <<= 1) {
        unsigned int o = (unsigned int)__shfl_xor((int)m, d, 64);
        m = o > m ? o : m;
      }
      win[e] = m;
      #pragma unroll
      for (int j = 0; j < 4; j++) if (key[j] == m) key[j] = 0u;
    }
    // decode (all lanes redundantly)
    float s8[8]; int i8[8];
    #pragma unroll
    for (int e = 0; e < 8; e++) {
      i8[e] = 255 - (int)(win[e] & 0xFFu);
      unsigned int os = win[e] & 0xFFFFFF00u;
      unsigned int u = (os & 0x80000000u) ? (os ^ 0x80000000u) : ~os;
      s8[e] = __builtin_bit_cast(float, u);
    }
    float m0 = s8[0], sum = 0.f, we[8];
    #pragma unroll
    for (int e = 0; e < 8; e++) { we[e] = expf(s8[e] - m0); sum += we[e]; }
    float inv = 1.f / sum;
    // PV gather: lane l owns cols 4l..4l+3 (f32x4, contiguous 1KB per slot)
    f32x4 accv = {0.f, 0.f, 0.f, 0.f};
    #pragma unroll
    for (int e = 0; e < 8; e++) {
      float wk = we[e] * inv;
      f32x4 p = *(const f32x4*)(PV + (size_t)i8[e] * 256 + lane * 4);
      #pragma unroll
      for (int j = 0; j < 4; j++) accv[j] += wk * p[j];
    }
    u16x4 o;
    #pragma unroll
    for (int j = 0; j < 4; j++) o[j] = f2bf(gelu_tanh(accv[j]));
    *(u16x4*)&D[(size_t)(row0 + row) * 256 + lane * 4] = o;
    if (lane == 0) gates[row0 + row] = 1.f / (1.f + expf(-m0));
  }
}

// ============================ K3: up-GEMM + epilogue ============================
// out[r,h] = primary[r,h] + gate[r] * (D[r,:] @ vup[h,:])   K=256
// 1024 blocks (64 row x 16 col tiles), XCD-chunk swizzle, 4 waves 2x2.
// primary prefetch is DOUBLE-BUFFERED per 32-row chunk (pref[2][4] = 32 VGPRs,
// statically indexed in the unrolled chunk loop) so we stay under the
// launch_bounds(256,4) 128-VGPR cap — the R5 pref[4][4] variant spilled to
// scratch (WRITE_SIZE doubled).  Chunk 0 loads issue before the K-loop
// (hidden under GEMM); chunk c+1 loads issue during chunk c's stage phase.
union KOutLds {
  unsigned short AB[2][128 * 64];  // As = AB[0], Bs = AB[1]  (32 KB)
  float stage[32 * 132];           // 16.5 KB, inside AB footprint
};
__global__ __launch_bounds__(256, 4) void k_out(const float* __restrict__ primary,
                                                float* __restrict__ out,
                                                unsigned char* __restrict__ ws) {
  const unsigned short* D = (const unsigned short*)(ws + WS_D);
  const unsigned short* vup = (const unsigned short*)(ws + WS_VUP);
  const float* gates = (const float*)(ws + WS_GATE);
  __shared__ __align__(16) KOutLds u;
  __shared__ float gate_s[128];
  unsigned short* As = u.AB[0];
  unsigned short* Bs = u.AB[1];
  int t = threadIdx.x, lane = t & 63, w = t >> 6;
  int bid = blockIdx.x;
  int L = (bid & 7) * 128 + (bid >> 3);   // bijective: 1024 % 8 == 0
  int rt = L >> 4, ct = L & 15;
  int wm = w >> 1, wn = w & 1;
  // per-chunk primary prefetch base: thread t covers rows {chunk*32+i*8+(t>>5)},
  // cols ct*128 + (t&31)*4 .. +3
  const float* pbase = primary + (size_t)(rt * 128 + (t >> 5)) * 2048 + ct * 128 + (t & 31) * 4;
  f32x4 pref[2][4];
  #pragma unroll
  for (int i = 0; i < 4; i++)   // chunk 0 -> pref[0], hides under whole GEMM
    pref[0][i] = *(const f32x4*)(pbase + (size_t)(i * 8) * 2048);
  if (t < 128) gate_s[t] = gates[rt * 128 + t];
  f32x4 acc[4][4] = {};
  for (int k0 = 0; k0 < 256; k0 += 64) {
    __syncthreads();
    #pragma unroll
    for (int i = 0; i < 4; i++) {
      int id = i * 256 + t, r = id >> 3, c = id & 7;
      int sw8 = (c ^ (r & 7)) * 8;
      *(u16x8*)&As[r * 64 + sw8] = *(const u16x8*)&D[(size_t)(rt * 128 + r) * 256 + k0 + c * 8];
      *(u16x8*)&Bs[r * 64 + sw8] = *(const u16x8*)&vup[(size_t)(ct * 128 + r) * 256 + k0 + c * 8];
    }
    __syncthreads();
    #pragma unroll
    for (int kk = 0; kk < 2; kk++) {
      int ck = kk * 4 + (lane >> 4);
      bf16x8 a[4], b[4];
      #pragma unroll
      for (int mf = 0; mf < 4; mf++) {
        int ar = wm * 64 + mf * 16 + (lane & 15);
        a[mf] = as_bf16(*(const u16x8*)&As[ar * 64 + ((ck ^ (ar & 7)) * 8)]);
      }
      #pragma unroll
      for (int nf = 0; nf < 4; nf++) {
        int br = wn * 64 + nf * 16 + (lane & 15);
        b[nf] = as_bf16(*(const u16x8*)&Bs[br * 64 + ((ck ^ (br & 7)) * 8)]);
      }
      #pragma unroll
      for (int mf = 0; mf < 4; mf++)
        #pragma unroll
        for (int nf = 0; nf < 4; nf++)
          acc[mf][nf] = __builtin_amdgcn_mfma_f32_16x16x32_bf16(a[mf], b[nf], acc[mf][nf], 0, 0, 0);
    }
  }
  // ---- coalesced epilogue: 4 chunks of 32 rows x 128 cols ----
  #pragma unroll
  for (int c = 0; c < 4; c++) {
    __syncthreads();   // prior readers of LDS done
    if (wm == (c >> 1)) {
      #pragma unroll
      for (int mi = 0; mi < 2; mi++) {
        int mf = (c & 1) * 2 + mi;
        #pragma unroll
        for (int nf = 0; nf < 4; nf++) {
          int col = wn * 64 + nf * 16 + (lane & 15);
          #pragma unroll
          for (int j = 0; j < 4; j++) {
            int r = mi * 16 + (lane >> 4) * 4 + j;
            u.stage[r * 132 + col] = acc[mf][nf][j];
          }
        }
      }
    }
    if (c < 3) {  // prefetch chunk c+1's primary (hidden under stage+store)
      #pragma unroll
      for (int i = 0; i < 4; i++)
        pref[(c + 1) & 1][i] = *(const f32x4*)(pbase + (size_t)((c + 1) * 32 + i * 8) * 2048);
    }
    __syncthreads();
    #pragma unroll
    for (int i = 0; i < 4; i++) {
      int idx = i * 256 + t, r = idx >> 5, c4 = idx & 31;
      int row = rt * 128 + c * 32 + r;
      size_t o = (size_t)row * 2048 + ct * 128 + c4 * 4;
      f32x4 p = pref[c & 1][i];
      f32x4 s = *(const f32x4*)&u.stage[r * 132 + c4 * 4];
      float g = gate_s[c * 32 + r];
      f32x4 ov;
      #pragma unroll
      for (int j = 0; j < 4; j++) ov[j] = p[j] + g * s[j];
      *(f32x4*)(out + o) = ov;
    }
  }
}

// ============================ launch ============================
extern "C" void kernel_launch(void* const* d_in, const int* in_sizes, int n_in,
                              void* d_out, int out_size, void* d_ws, size_t ws_size,
                              hipStream_t stream) {
  const float* hs      = (const float*)d_in[0];
  const float* primary = (const float*)d_in[1];
  const float* qw      = (const float*)d_in[2];
  const float* sk      = (const float*)d_in[3];
  const float* sv      = (const float*)d_in[4];
  const float* rel     = (const float*)d_in[5];
  const float* vdw     = (const float*)d_in[6];
  const float* vup     = (const float*)d_in[7];
  unsigned char* ws = (unsigned char*)d_ws;
  float* out = (float*)d_out;

  k_prep<<<dim3(256), dim3(256), 0, stream>>>(qw, sk, sv, vdw, vup, rel, ws);
  k_pv<<<dim3(64), dim3(256), 0, stream>>>(ws);
  k_query<<<dim3(512), dim3(256), 0, stream>>>(hs, ws);
  k_score<<<dim3(512), dim3(256), 0, stream>>>(ws);
  k_out<<<dim3(1024), dim3(256), 0, stream>>>(primary, out, ws);
}

// Round 7
// 96.469 us; speedup vs baseline: 1.2893x; 1.1290x over previous
//
#include <hip/hip_runtime.h>
#include <stdint.h>

// ============================ problem dims ============================
// hidden_states [4,2048,2048] f32, rows R=8192, H=2048, BD=N=VBD=256, top-8
// out = primary + sigmoid(top1) * gelu_lowrank(softmax_top8 @ gathered vals)
// Key restructure: down-proj is linear -> precompute PV = slot_values @ Wd^T
// (256x256) and gather from PV instead of materializing aux[8192][2048].

typedef float f32x4 __attribute__((ext_vector_type(4)));
typedef unsigned short u16x8 __attribute__((ext_vector_type(8)));
typedef unsigned short u16x4 __attribute__((ext_vector_type(4)));
typedef __bf16 bf16x8 __attribute__((ext_vector_type(8)));

// ============================ ws layout (bytes) ============================
#define WS_QW    0u          // u16 [256*2048]  q_proj_w bf16
#define WS_SK    1048576u    // u16 [256*256]   slot_keys bf16
#define WS_SV    1179648u    // u16 [256*2048]  slot_values bf16
#define WS_VDW   2228224u    // u16 [256*2048]  value_down_w bf16
#define WS_VUP   3276800u    // u16 [2048*256]  value_up_w bf16
#define WS_REL   4325376u    // f32 [256]       log(reliability)
#define WS_PV    4326400u    // f32 [256*256]   slot_values @ Wd^T
#define WS_GATE  4588544u    // f32 [8192]      sigmoid(top1)
#define WS_QP    4621312u    // f32 [2][8192][256] query split-K partials
#define WS_D     21398528u   // u16 [8192*256]  gelu(down) bf16
// total ~24.4 MB

static __device__ __forceinline__ unsigned short f2bf(float f) {
  union { float f; unsigned int u; } v; v.f = f;
  unsigned int r = v.u + 0x7FFFu + ((v.u >> 16) & 1u);
  return (unsigned short)(r >> 16);
}
static __device__ __forceinline__ bf16x8 as_bf16(u16x8 v) {
  return __builtin_bit_cast(bf16x8, v);
}
static __device__ __forceinline__ float gelu_tanh(float x) {
  float u = 0.7978845608028654f * (x + 0.044715f * x * x * x);
  return 0.5f * x * (1.0f + tanhf(u));
}

// ============================ K0: convert weights ============================
__global__ void k_prep(const float* __restrict__ qw, const float* __restrict__ sk,
                       const float* __restrict__ sv, const float* __restrict__ vdw,
                       const float* __restrict__ vup, const float* __restrict__ rel,
                       unsigned char* __restrict__ ws) {
  unsigned short* o_qw  = (unsigned short*)(ws + WS_QW);
  unsigned short* o_sk  = (unsigned short*)(ws + WS_SK);
  unsigned short* o_sv  = (unsigned short*)(ws + WS_SV);
  unsigned short* o_vdw = (unsigned short*)(ws + WS_VDW);
  unsigned short* o_vup = (unsigned short*)(ws + WS_VUP);
  float* o_rel = (float*)(ws + WS_REL);
  int tid = blockIdx.x * blockDim.x + threadIdx.x;
  int stride = gridDim.x * blockDim.x;
  for (int g = tid; g < 540736; g += stride) {
    const float* src; unsigned short* dst; int i;
    if      (g < 131072) { src = qw;  dst = o_qw;  i = g; }
    else if (g < 147456) { src = sk;  dst = o_sk;  i = g - 131072; }
    else if (g < 278528) { src = sv;  dst = o_sv;  i = g - 147456; }
    else if (g < 409600) { src = vdw; dst = o_vdw; i = g - 278528; }
    else if (g < 540672) { src = vup; dst = o_vup; i = g - 409600; }
    else {
      int i4 = (g - 540672) * 4;
      #pragma unroll
      for (int j = 0; j < 4; j++) o_rel[i4 + j] = logf(fmaxf(rel[i4 + j], 1e-10f));
      continue;
    }
    f32x4 v = *(const f32x4*)(src + (size_t)i * 4);
    u16x4 o;
    #pragma unroll
    for (int j = 0; j < 4; j++) o[j] = f2bf(v[j]);
    *(u16x4*)(dst + (size_t)i * 4) = o;
  }
}

// ============================ K_PV: PV = sv @ vdw^T ============================
// 64 blocks, each a 32x32 tile over K=2048. 4 waves, one 16x16 frag each.
__global__ __launch_bounds__(256, 2) void k_pv(unsigned char* __restrict__ ws) {
  const unsigned short* sv  = (const unsigned short*)(ws + WS_SV);
  const unsigned short* vdw = (const unsigned short*)(ws + WS_VDW);
  float* PV = (float*)(ws + WS_PV);
  __shared__ __align__(16) unsigned short As[32 * 64];
  __shared__ __align__(16) unsigned short Bs[32 * 64];
  int t = threadIdx.x, lane = t & 63, w = t >> 6;
  int nt = blockIdx.x >> 3, vt = blockIdx.x & 7;
  int mf = w >> 1, nf = w & 1;
  f32x4 acc = {0.f, 0.f, 0.f, 0.f};
  int r = t >> 3, c = t & 7;
  int sw8 = (c ^ (r & 7)) * 8;
  for (int k0 = 0; k0 < 2048; k0 += 64) {
    __syncthreads();
    *(u16x8*)&As[r * 64 + sw8] = *(const u16x8*)&sv[(size_t)(nt * 32 + r) * 2048 + k0 + c * 8];
    *(u16x8*)&Bs[r * 64 + sw8] = *(const u16x8*)&vdw[(size_t)(vt * 32 + r) * 2048 + k0 + c * 8];
    __syncthreads();
    #pragma unroll
    for (int kk = 0; kk < 2; kk++) {
      int ck = kk * 4 + (lane >> 4);
      int ar = mf * 16 + (lane & 15);
      int br = nf * 16 + (lane & 15);
      bf16x8 a = as_bf16(*(const u16x8*)&As[ar * 64 + ((ck ^ (ar & 7)) * 8)]);
      bf16x8 b = as_bf16(*(const u16x8*)&Bs[br * 64 + ((ck ^ (br & 7)) * 8)]);
      acc = __builtin_amdgcn_mfma_f32_16x16x32_bf16(a, b, acc, 0, 0, 0);
    }
  }
  int row = nt * 32 + mf * 16 + (lane >> 4) * 4;
  int col = vt * 32 + nf * 16 + (lane & 15);
  #pragma unroll
  for (int j = 0; j < 4; j++) PV[(row + j) * 256 + col] = acc[j];
}

// ============================ K1: query GEMM (split-K=2, pipelined) ============================
// qpart[ks][r][d] = hs[r, ks*1024 : +1024] @ qw^T.  BM=32, BN=256(all of BD).
// 512 blocks (256 row tiles x 2 k-slices) -> 4 blocks/CU.  Register-prefetch
// pipeline: issue tile t+1's global loads before the MFMA phase.
__global__ __launch_bounds__(256, 4) void k_query(const float* __restrict__ hs,
                                                  unsigned char* __restrict__ ws) {
  const unsigned short* qw = (const unsigned short*)(ws + WS_QW);
  float* qp = (float*)(ws + WS_QP);
  __shared__ __align__(16) unsigned short As[32 * 64];    // 4 KB
  __shared__ __align__(16) unsigned short Bs[256 * 64];   // 32 KB
  int t = threadIdx.x, lane = t & 63, w = t >> 6;
  int rt = blockIdx.x >> 1, ks = blockIdx.x & 1;
  int row0 = rt * 32, kbase = ks * 1024;
  f32x4 acc[2][4] = {};
  int sr = t >> 3, sc = t & 7;   // staging coords: 32 rows x 8 chunks of 8
  const float* aptr = hs + (size_t)(row0 + sr) * 2048 + kbase + sc * 8;
  const unsigned short* bptr = qw + (size_t)sr * 2048 + kbase + sc * 8;
  f32x4 pa0, pa1;
  u16x8 pb0, pb1, pb2, pb3, pb4, pb5, pb6, pb7;
  // prologue: tile 0 -> regs
  pa0 = *(const f32x4*)(aptr);
  pa1 = *(const f32x4*)(aptr + 4);
  pb0 = *(const u16x8*)(bptr + (size_t)0 * 32 * 2048);
  pb1 = *(const u16x8*)(bptr + (size_t)1 * 32 * 2048);
  pb2 = *(const u16x8*)(bptr + (size_t)2 * 32 * 2048);
  pb3 = *(const u16x8*)(bptr + (size_t)3 * 32 * 2048);
  pb4 = *(const u16x8*)(bptr + (size_t)4 * 32 * 2048);
  pb5 = *(const u16x8*)(bptr + (size_t)5 * 32 * 2048);
  pb6 = *(const u16x8*)(bptr + (size_t)6 * 32 * 2048);
  pb7 = *(const u16x8*)(bptr + (size_t)7 * 32 * 2048);
  for (int kt = 0; kt < 16; kt++) {
    __syncthreads();   // previous tile's LDS readers done
    {  // stage regs -> LDS (A: fp32->bf16)
      u16x8 o;
      #pragma unroll
      for (int j = 0; j < 4; j++) { o[j] = f2bf(pa0[j]); o[4 + j] = f2bf(pa1[j]); }
      *(u16x8*)&As[sr * 64 + ((sc ^ (sr & 7)) * 8)] = o;
      u16x8 pb[8] = {pb0, pb1, pb2, pb3, pb4, pb5, pb6, pb7};
      #pragma unroll
      for (int i = 0; i < 8; i++) {
        int n = i * 32 + sr;
        *(u16x8*)&Bs[n * 64 + ((sc ^ (n & 7)) * 8)] = pb[i];
      }
    }
    __syncthreads();
    if (kt < 15) {  // prefetch tile kt+1 into regs (overlaps MFMA below)
      int off = (kt + 1) * 64;
      pa0 = *(const f32x4*)(aptr + off);
      pa1 = *(const f32x4*)(aptr + off + 4);
      pb0 = *(const u16x8*)(bptr + (size_t)0 * 32 * 2048 + off);
      pb1 = *(const u16x8*)(bptr + (size_t)1 * 32 * 2048 + off);
      pb2 = *(const u16x8*)(bptr + (size_t)2 * 32 * 2048 + off);
      pb3 = *(const u16x8*)(bptr + (size_t)3 * 32 * 2048 + off);
      pb4 = *(const u16x8*)(bptr + (size_t)4 * 32 * 2048 + off);
      pb5 = *(const u16x8*)(bptr + (size_t)5 * 32 * 2048 + off);
      pb6 = *(const u16x8*)(bptr + (size_t)6 * 32 * 2048 + off);
      pb7 = *(const u16x8*)(bptr + (size_t)7 * 32 * 2048 + off);
    }
    #pragma unroll
    for (int kk = 0; kk < 2; kk++) {
      int ck = kk * 4 + (lane >> 4);
      bf16x8 a[2], b[4];
      #pragma unroll
      for (int mf = 0; mf < 2; mf++) {
        int arow = mf * 16 + (lane & 15);
        a[mf] = as_bf16(*(const u16x8*)&As[arow * 64 + ((ck ^ (arow & 7)) * 8)]);
      }
      #pragma unroll
      for (int nf = 0; nf < 4; nf++) {
        int brow = w * 64 + nf * 16 + (lane & 15);
        b[nf] = as_bf16(*(const u16x8*)&Bs[brow * 64 + ((ck ^ (brow & 7)) * 8)]);
      }
      #pragma unroll
      for (int mf = 0; mf < 2; mf++)
        #pragma unroll
        for (int nf = 0; nf < 4; nf++)
          acc[mf][nf] = __builtin_amdgcn_mfma_f32_16x16x32_bf16(a[mf], b[nf], acc[mf][nf], 0, 0, 0);
    }
  }
  float* outp = qp + (size_t)ks * 8192 * 256;
  #pragma unroll
  for (int mf = 0; mf < 2; mf++) {
    int row = row0 + mf * 16 + (lane >> 4) * 4;
    #pragma unroll
    for (int nf = 0; nf < 4; nf++) {
      int col = w * 64 + nf * 16 + (lane & 15);
      #pragma unroll
      for (int j = 0; j < 4; j++) outp[(size_t)(row + j) * 256 + col] = acc[mf][nf][j];
    }
  }
}

// ============================ K2: scores + wave-parallel top8 + PV gather ============================
// 512 blocks x 16 rows. Phase 1: Q=qp0+qp1 -> bf16 LDS. Phase 2: MFMA scores
// -> Ss (stride 260 f32, per-row reads contiguous). Phase 3: one WAVE per row:
// pack (ordered-score|255-idx) u32, 8x {max4 + 6-step shfl_xor butterfly max,
// owner masks winner}; all lanes decode winners redundantly (no LDS, no
// divergence), softmax + gate, coalesced f32x4 PV gather, gelu -> D bf16.
#define QSTR 264   // ushort stride
#define SSTR 260   // f32 stride: 1040B row -> 16B aligned, contiguous reads
__global__ __launch_bounds__(256, 4) void k_score(unsigned char* __restrict__ ws) {
  const float* qp = (const float*)(ws + WS_QP);
  const unsigned short* sk = (const unsigned short*)(ws + WS_SK);
  const float* relm = (const float*)(ws + WS_REL);
  const float* PV = (const float*)(ws + WS_PV);
  float* gates = (float*)(ws + WS_GATE);
  unsigned short* D = (unsigned short*)(ws + WS_D);
  __shared__ __align__(16) unsigned short Qs[16 * QSTR];
  __shared__ __align__(16) float Ss[16 * SSTR];
  int t = threadIdx.x, lane = t & 63, w = t >> 6;
  int row0 = blockIdx.x * 16;
  // phase 1: query = qpart0 + qpart1 -> bf16 -> LDS (16 rows x 256 cols)
  #pragma unroll
  for (int i = 0; i < 4; i++) {
    int id = i * 256 + t, r = id >> 6, c4 = id & 63;
    const float* p0 = qp + (size_t)(row0 + r) * 256 + c4 * 4;
    f32x4 a = *(const f32x4*)p0;
    f32x4 b = *(const f32x4*)(p0 + 8192 * 256);
    u16x4 o;
    #pragma unroll
    for (int j = 0; j < 4; j++) o[j] = f2bf(a[j] + b[j]);
    *(u16x4*)&Qs[r * QSTR + c4 * 4] = o;
  }
  __syncthreads();
  // phase 2: scores[16][256] = Q @ sk^T / 16 + rel_mask
  {
    f32x4 acc[4] = {};
    for (int ksb = 0; ksb < 8; ksb++) {
      int ck = lane >> 4;
      bf16x8 a = as_bf16(*(const u16x8*)&Qs[(lane & 15) * QSTR + ksb * 32 + ck * 8]);
      #pragma unroll
      for (int nf = 0; nf < 4; nf++) {
        int n = w * 64 + nf * 16 + (lane & 15);
        bf16x8 b = as_bf16(*(const u16x8*)&sk[(size_t)n * 256 + ksb * 32 + ck * 8]);
        acc[nf] = __builtin_amdgcn_mfma_f32_16x16x32_bf16(a, b, acc[nf], 0, 0, 0);
      }
    }
    #pragma unroll
    for (int nf = 0; nf < 4; nf++) {
      int n = w * 64 + nf * 16 + (lane & 15);
      float rm = relm[n];
      int rr = (lane >> 4) * 4;
      #pragma unroll
      for (int j = 0; j < 4; j++) Ss[(rr + j) * SSTR + n] = acc[nf][j] * 0.0625f + rm;
    }
  }
  __syncthreads();
  // phase 3: wave w handles rows w*4 .. w*4+3
  for (int rr = 0; rr < 4; rr++) {
    int row = w * 4 + rr;
    f32x4 sv4 = *(const f32x4*)&Ss[row * SSTR + lane * 4];
    unsigned int key[4];
    #pragma unroll
    for (int j = 0; j < 4; j++) {
      unsigned int u = __builtin_bit_cast(unsigned int, sv4[j]);
      unsigned int os = (u & 0x80000000u) ? ~u : (u | 0x80000000u);
      key[j] = (os & 0xFFFFFF00u) | (unsigned int)(255 - (lane * 4 + j));
    }
    unsigned int win[8];
    #pragma unroll
    for (int e = 0; e < 8; e++) {
      unsigned int m01 = key[0] > key[1] ? key[0] : key[1];
      unsigned int m23 = key[2] > key[3] ? key[2] : key[3];
      unsigned int m = m01 > m23 ? m01 : m23;
      #pragma unroll
      for (int d = 1; d < 64; d <<= 1) {
        unsigned int o = (unsigned int)__shfl_xor((int)m, d, 64);
        m = o > m ? o : m;
      }
      win[e] = m;
      #pragma unroll
      for (int j = 0; j < 4; j++) if (key[j] == m) key[j] = 0u;
    }
    // decode (all lanes redundantly)
    float s8[8]; int i8[8];
    #pragma unroll
    for (int e = 0; e < 8; e++) {
      i8[e] = 255 - (int)(win[e] & 0xFFu);
      unsigned int os = win[e] & 0xFFFFFF00u;
      unsigned int u = (os & 0x80000000u) ? (os ^ 0x80000000u) : ~os;
      s8[e] = __builtin_bit_cast(float, u);
    }
    float m0 = s8[0], sum = 0.f, we[8];
    #pragma unroll
    for (int e = 0; e < 8; e++) { we[e] = expf(s8[e] - m0); sum += we[e]; }
    float inv = 1.f / sum;
    // PV gather: lane l owns cols 4l..4l+3 (f32x4, contiguous 1KB per slot)
    f32x4 accv = {0.f, 0.f, 0.f, 0.f};
    #pragma unroll
    for (int e = 0; e < 8; e++) {
      float wk = we[e] * inv;
      f32x4 p = *(const f32x4*)(PV + (size_t)i8[e] * 256 + lane * 4);
      #pragma unroll
      for (int j = 0; j < 4; j++) accv[j] += wk * p[j];
    }
    u16x4 o;
    #pragma unroll
    for (int j = 0; j < 4; j++) o[j] = f2bf(gelu_tanh(accv[j]));
    *(u16x4*)&D[(size_t)(row0 + row) * 256 + lane * 4] = o;
    if (lane == 0) gates[row0 + row] = 1.f / (1.f + expf(-m0));
  }
}

// ============================ K3: up-GEMM + epilogue ============================
// out[r,h] = primary[r,h] + gate[r] * (D[r,:] @ vup[h,:])   K=256
// 1024 blocks (64 row x 16 col tiles), XCD-chunk swizzle, 4 waves 2x2.
// gfx950 unified reg file: acc[4][4] = 64 regs + ~64 arch regs is exactly the
// (256,4) 128-reg cap -> ANY prefetch spilled (R5: WRITE 2x; R6: +22MB).
// Fix: __launch_bounds__(256,3) (~170-reg cap) + pref[2][4] double buffer.
// Chunk 0 loads issue before the K-loop (hidden under GEMM); chunk c+1 loads
// issue during chunk c's stage phase (hidden under LDS restage + stores).
union KOutLds {
  unsigned short AB[2][128 * 64];  // As = AB[0], Bs = AB[1]  (32 KB)
  float stage[32 * 132];           // 16.5 KB, inside AB footprint
};
__global__ __launch_bounds__(256, 3) void k_out(const float* __restrict__ primary,
                                                float* __restrict__ out,
                                                unsigned char* __restrict__ ws) {
  const unsigned short* D = (const unsigned short*)(ws + WS_D);
  const unsigned short* vup = (const unsigned short*)(ws + WS_VUP);
  const float* gates = (const float*)(ws + WS_GATE);
  __shared__ __align__(16) KOutLds u;
  __shared__ float gate_s[128];
  unsigned short* As = u.AB[0];
  unsigned short* Bs = u.AB[1];
  int t = threadIdx.x, lane = t & 63, w = t >> 6;
  int bid = blockIdx.x;
  int L = (bid & 7) * 128 + (bid >> 3);   // bijective: 1024 % 8 == 0
  int rt = L >> 4, ct = L & 15;
  int wm = w >> 1, wn = w & 1;
  // per-chunk primary prefetch base: thread t covers rows {chunk*32+i*8+(t>>5)},
  // cols ct*128 + (t&31)*4 .. +3
  const float* pbase = primary + (size_t)(rt * 128 + (t >> 5)) * 2048 + ct * 128 + (t & 31) * 4;
  f32x4 pref[2][4];
  #pragma unroll
  for (int i = 0; i < 4; i++)   // chunk 0 -> pref[0], hides under whole GEMM
    pref[0][i] = *(const f32x4*)(pbase + (size_t)(i * 8) * 2048);
  if (t < 128) gate_s[t] = gates[rt * 128 + t];
  f32x4 acc[4][4] = {};
  for (int k0 = 0; k0 < 256; k0 += 64) {
    __syncthreads();
    #pragma unroll
    for (int i = 0; i < 4; i++) {
      int id = i * 256 + t, r = id >> 3, c = id & 7;
      int sw8 = (c ^ (r & 7)) * 8;
      *(u16x8*)&As[r * 64 + sw8] = *(const u16x8*)&D[(size_t)(rt * 128 + r) * 256 + k0 + c * 8];
      *(u16x8*)&Bs[r * 64 + sw8] = *(const u16x8*)&vup[(size_t)(ct * 128 + r) * 256 + k0 + c * 8];
    }
    __syncthreads();
    #pragma unroll
    for (int kk = 0; kk < 2; kk++) {
      int ck = kk * 4 + (lane >> 4);
      bf16x8 a[4], b[4];
      #pragma unroll
      for (int mf = 0; mf < 4; mf++) {
        int ar = wm * 64 + mf * 16 + (lane & 15);
        a[mf] = as_bf16(*(const u16x8*)&As[ar * 64 + ((ck ^ (ar & 7)) * 8)]);
      }
      #pragma unroll
      for (int nf = 0; nf < 4; nf++) {
        int br = wn * 64 + nf * 16 + (lane & 15);
        b[nf] = as_bf16(*(const u16x8*)&Bs[br * 64 + ((ck ^ (br & 7)) * 8)]);
      }
      #pragma unroll
      for (int mf = 0; mf < 4; mf++)
        #pragma unroll
        for (int nf = 0; nf < 4; nf++)
          acc[mf][nf] = __builtin_amdgcn_mfma_f32_16x16x32_bf16(a[mf], b[nf], acc[mf][nf], 0, 0, 0);
    }
  }
  // ---- coalesced epilogue: 4 chunks of 32 rows x 128 cols ----
  #pragma unroll
  for (int c = 0; c < 4; c++) {
    __syncthreads();   // prior readers of LDS done
    if (wm == (c >> 1)) {
      #pragma unroll
      for (int mi = 0; mi < 2; mi++) {
        int mf = (c & 1) * 2 + mi;
        #pragma unroll
        for (int nf = 0; nf < 4; nf++) {
          int col = wn * 64 + nf * 16 + (lane & 15);
          #pragma unroll
          for (int j = 0; j < 4; j++) {
            int r = mi * 16 + (lane >> 4) * 4 + j;
            u.stage[r * 132 + col] = acc[mf][nf][j];
          }
        }
      }
    }
    if (c < 3) {  // prefetch chunk c+1's primary (hidden under stage+store)
      #pragma unroll
      for (int i = 0; i < 4; i++)
        pref[(c + 1) & 1][i] = *(const f32x4*)(pbase + (size_t)((c + 1) * 32 + i * 8) * 2048);
    }
    __syncthreads();
    #pragma unroll
    for (int i = 0; i < 4; i++) {
      int idx = i * 256 + t, r = idx >> 5, c4 = idx & 31;
      int row = rt * 128 + c * 32 + r;
      size_t o = (size_t)row * 2048 + ct * 128 + c4 * 4;
      f32x4 p = pref[c & 1][i];
      f32x4 s = *(const f32x4*)&u.stage[r * 132 + c4 * 4];
      float g = gate_s[c * 32 + r];
      f32x4 ov;
      #pragma unroll
      for (int j = 0; j < 4; j++) ov[j] = p[j] + g * s[j];
      *(f32x4*)(out + o) = ov;
    }
  }
}

// ============================ launch ============================
extern "C" void kernel_launch(void* const* d_in, const int* in_sizes, int n_in,
                              void* d_out, int out_size, void* d_ws, size_t ws_size,
                              hipStream_t stream) {
  const float* hs      = (const float*)d_in[0];
  const float* primary = (const float*)d_in[1];
  const float* qw      = (const float*)d_in[2];
  const float* sk      = (const float*)d_in[3];
  const float* sv      = (const float*)d_in[4];
  const float* rel     = (const float*)d_in[5];
  const float* vdw     = (const float*)d_in[6];
  const float* vup     = (const float*)d_in[7];
  unsigned char* ws = (unsigned char*)d_ws;
  float* out = (float*)d_out;

  k_prep<<<dim3(256), dim3(256), 0, stream>>>(qw, sk, sv, vdw, vup, rel, ws);
  k_pv<<<dim3(64), dim3(256), 0, stream>>>(ws);
  k_query<<<dim3(512), dim3(256), 0, stream>>>(hs, ws);
  k_score<<<dim3(512), dim3(256), 0, stream>>>(ws);
  k_out<<<dim3(1024), dim3(256), 0, stream>>>(primary, out, ws);
}

// Round 8
// 95.098 us; speedup vs baseline: 1.3079x; 1.0144x over previous
//
#include <hip/hip_runtime.h>
#include <stdint.h>

// ============================ problem dims ============================
// hidden_states [4,2048,2048] f32, rows R=8192, H=2048, BD=N=VBD=256, top-8
// out = primary + sigmoid(top1) * gelu_lowrank(softmax_top8 @ gathered vals)
// Key restructure: down-proj is linear -> precompute PV = slot_values @ Wd^T
// (256x256) and gather from PV instead of materializing aux[8192][2048].

typedef float f32x4 __attribute__((ext_vector_type(4)));
typedef unsigned short u16x8 __attribute__((ext_vector_type(8)));
typedef unsigned short u16x4 __attribute__((ext_vector_type(4)));
typedef __bf16 bf16x8 __attribute__((ext_vector_type(8)));

// ============================ ws layout (bytes) ============================
#define WS_QW    0u          // u16 [256*2048]  q_proj_w bf16
#define WS_SK    1048576u    // u16 [256*256]   slot_keys bf16
#define WS_SV    1179648u    // u16 [256*2048]  slot_values bf16
#define WS_VDW   2228224u    // u16 [256*2048]  value_down_w bf16
#define WS_VUP   3276800u    // u16 [2048*256]  value_up_w bf16
#define WS_REL   4325376u    // f32 [256]       log(reliability)
#define WS_PV    4326400u    // f32 [256*256]   slot_values @ Wd^T
#define WS_GATE  4588544u    // f32 [8192]      sigmoid(top1)
#define WS_QP    4621312u    // f32 [2][8192][256] query split-K partials
#define WS_D     21398528u   // u16 [8192*256]  gelu(down) bf16
// total ~24.4 MB

static __device__ __forceinline__ unsigned short f2bf(float f) {
  union { float f; unsigned int u; } v; v.f = f;
  unsigned int r = v.u + 0x7FFFu + ((v.u >> 16) & 1u);
  return (unsigned short)(r >> 16);
}
static __device__ __forceinline__ bf16x8 as_bf16(u16x8 v) {
  return __builtin_bit_cast(bf16x8, v);
}
static __device__ __forceinline__ float gelu_tanh(float x) {
  float u = 0.7978845608028654f * (x + 0.044715f * x * x * x);
  return 0.5f * x * (1.0f + tanhf(u));
}

// ============================ K0: convert weights ============================
__global__ void k_prep(const float* __restrict__ qw, const float* __restrict__ sk,
                       const float* __restrict__ sv, const float* __restrict__ vdw,
                       const float* __restrict__ vup, const float* __restrict__ rel,
                       unsigned char* __restrict__ ws) {
  unsigned short* o_qw  = (unsigned short*)(ws + WS_QW);
  unsigned short* o_sk  = (unsigned short*)(ws + WS_SK);
  unsigned short* o_sv  = (unsigned short*)(ws + WS_SV);
  unsigned short* o_vdw = (unsigned short*)(ws + WS_VDW);
  unsigned short* o_vup = (unsigned short*)(ws + WS_VUP);
  float* o_rel = (float*)(ws + WS_REL);
  int tid = blockIdx.x * blockDim.x + threadIdx.x;
  int stride = gridDim.x * blockDim.x;
  for (int g = tid; g < 540736; g += stride) {
    const float* src; unsigned short* dst; int i;
    if      (g < 131072) { src = qw;  dst = o_qw;  i = g; }
    else if (g < 147456) { src = sk;  dst = o_sk;  i = g - 131072; }
    else if (g < 278528) { src = sv;  dst = o_sv;  i = g - 147456; }
    else if (g < 409600) { src = vdw; dst = o_vdw; i = g - 278528; }
    else if (g < 540672) { src = vup; dst = o_vup; i = g - 409600; }
    else {
      int i4 = (g - 540672) * 4;
      #pragma unroll
      for (int j = 0; j < 4; j++) o_rel[i4 + j] = logf(fmaxf(rel[i4 + j], 1e-10f));
      continue;
    }
    f32x4 v = *(const f32x4*)(src + (size_t)i * 4);
    u16x4 o;
    #pragma unroll
    for (int j = 0; j < 4; j++) o[j] = f2bf(v[j]);
    *(u16x4*)(dst + (size_t)i * 4) = o;
  }
}

// ============================ K_PV: PV = sv @ vdw^T ============================
// 64 blocks, each a 32x32 tile over K=2048. 4 waves, one 16x16 frag each.
__global__ __launch_bounds__(256, 2) void k_pv(unsigned char* __restrict__ ws) {
  const unsigned short* sv  = (const unsigned short*)(ws + WS_SV);
  const unsigned short* vdw = (const unsigned short*)(ws + WS_VDW);
  float* PV = (float*)(ws + WS_PV);
  __shared__ __align__(16) unsigned short As[32 * 64];
  __shared__ __align__(16) unsigned short Bs[32 * 64];
  int t = threadIdx.x, lane = t & 63, w = t >> 6;
  int nt = blockIdx.x >> 3, vt = blockIdx.x & 7;
  int mf = w >> 1, nf = w & 1;
  f32x4 acc = {0.f, 0.f, 0.f, 0.f};
  int r = t >> 3, c = t & 7;
  int sw8 = (c ^ (r & 7)) * 8;
  for (int k0 = 0; k0 < 2048; k0 += 64) {
    __syncthreads();
    *(u16x8*)&As[r * 64 + sw8] = *(const u16x8*)&sv[(size_t)(nt * 32 + r) * 2048 + k0 + c * 8];
    *(u16x8*)&Bs[r * 64 + sw8] = *(const u16x8*)&vdw[(size_t)(vt * 32 + r) * 2048 + k0 + c * 8];
    __syncthreads();
    #pragma unroll
    for (int kk = 0; kk < 2; kk++) {
      int ck = kk * 4 + (lane >> 4);
      int ar = mf * 16 + (lane & 15);
      int br = nf * 16 + (lane & 15);
      bf16x8 a = as_bf16(*(const u16x8*)&As[ar * 64 + ((ck ^ (ar & 7)) * 8)]);
      bf16x8 b = as_bf16(*(const u16x8*)&Bs[br * 64 + ((ck ^ (br & 7)) * 8)]);
      acc = __builtin_amdgcn_mfma_f32_16x16x32_bf16(a, b, acc, 0, 0, 0);
    }
  }
  int row = nt * 32 + mf * 16 + (lane >> 4) * 4;
  int col = vt * 32 + nf * 16 + (lane & 15);
  #pragma unroll
  for (int j = 0; j < 4; j++) PV[(row + j) * 256 + col] = acc[j];
}

// ============================ K1: query GEMM (split-K=2, pipelined) ============================
// qpart[ks][r][d] = hs[r, ks*1024 : +1024] @ qw^T.  BM=32, BN=256(all of BD).
// 512 blocks (256 row tiles x 2 k-slices) -> 4 blocks/CU.  Register-prefetch
// pipeline: issue tile t+1's global loads before the MFMA phase.
__global__ __launch_bounds__(256, 4) void k_query(const float* __restrict__ hs,
                                                  unsigned char* __restrict__ ws) {
  const unsigned short* qw = (const unsigned short*)(ws + WS_QW);
  float* qp = (float*)(ws + WS_QP);
  __shared__ __align__(16) unsigned short As[32 * 64];    // 4 KB
  __shared__ __align__(16) unsigned short Bs[256 * 64];   // 32 KB
  int t = threadIdx.x, lane = t & 63, w = t >> 6;
  int rt = blockIdx.x >> 1, ks = blockIdx.x & 1;
  int row0 = rt * 32, kbase = ks * 1024;
  f32x4 acc[2][4] = {};
  int sr = t >> 3, sc = t & 7;   // staging coords: 32 rows x 8 chunks of 8
  const float* aptr = hs + (size_t)(row0 + sr) * 2048 + kbase + sc * 8;
  const unsigned short* bptr = qw + (size_t)sr * 2048 + kbase + sc * 8;
  f32x4 pa0, pa1;
  u16x8 pb0, pb1, pb2, pb3, pb4, pb5, pb6, pb7;
  // prologue: tile 0 -> regs
  pa0 = *(const f32x4*)(aptr);
  pa1 = *(const f32x4*)(aptr + 4);
  pb0 = *(const u16x8*)(bptr + (size_t)0 * 32 * 2048);
  pb1 = *(const u16x8*)(bptr + (size_t)1 * 32 * 2048);
  pb2 = *(const u16x8*)(bptr + (size_t)2 * 32 * 2048);
  pb3 = *(const u16x8*)(bptr + (size_t)3 * 32 * 2048);
  pb4 = *(const u16x8*)(bptr + (size_t)4 * 32 * 2048);
  pb5 = *(const u16x8*)(bptr + (size_t)5 * 32 * 2048);
  pb6 = *(const u16x8*)(bptr + (size_t)6 * 32 * 2048);
  pb7 = *(const u16x8*)(bptr + (size_t)7 * 32 * 2048);
  for (int kt = 0; kt < 16; kt++) {
    __syncthreads();   // previous tile's LDS readers done
    {  // stage regs -> LDS (A: fp32->bf16)
      u16x8 o;
      #pragma unroll
      for (int j = 0; j < 4; j++) { o[j] = f2bf(pa0[j]); o[4 + j] = f2bf(pa1[j]); }
      *(u16x8*)&As[sr * 64 + ((sc ^ (sr & 7)) * 8)] = o;
      u16x8 pb[8] = {pb0, pb1, pb2, pb3, pb4, pb5, pb6, pb7};
      #pragma unroll
      for (int i = 0; i < 8; i++) {
        int n = i * 32 + sr;
        *(u16x8*)&Bs[n * 64 + ((sc ^ (n & 7)) * 8)] = pb[i];
      }
    }
    __syncthreads();
    if (kt < 15) {  // prefetch tile kt+1 into regs (overlaps MFMA below)
      int off = (kt + 1) * 64;
      pa0 = *(const f32x4*)(aptr + off);
      pa1 = *(const f32x4*)(aptr + off + 4);
      pb0 = *(const u16x8*)(bptr + (size_t)0 * 32 * 2048 + off);
      pb1 = *(const u16x8*)(bptr + (size_t)1 * 32 * 2048 + off);
      pb2 = *(const u16x8*)(bptr + (size_t)2 * 32 * 2048 + off);
      pb3 = *(const u16x8*)(bptr + (size_t)3 * 32 * 2048 + off);
      pb4 = *(const u16x8*)(bptr + (size_t)4 * 32 * 2048 + off);
      pb5 = *(const u16x8*)(bptr + (size_t)5 * 32 * 2048 + off);
      pb6 = *(const u16x8*)(bptr + (size_t)6 * 32 * 2048 + off);
      pb7 = *(const u16x8*)(bptr + (size_t)7 * 32 * 2048 + off);
    }
    #pragma unroll
    for (int kk = 0; kk < 2; kk++) {
      int ck = kk * 4 + (lane >> 4);
      bf16x8 a[2], b[4];
      #pragma unroll
      for (int mf = 0; mf < 2; mf++) {
        int arow = mf * 16 + (lane & 15);
        a[mf] = as_bf16(*(const u16x8*)&As[arow * 64 + ((ck ^ (arow & 7)) * 8)]);
      }
      #pragma unroll
      for (int nf = 0; nf < 4; nf++) {
        int brow = w * 64 + nf * 16 + (lane & 15);
        b[nf] = as_bf16(*(const u16x8*)&Bs[brow * 64 + ((ck ^ (brow & 7)) * 8)]);
      }
      #pragma unroll
      for (int mf = 0; mf < 2; mf++)
        #pragma unroll
        for (int nf = 0; nf < 4; nf++)
          acc[mf][nf] = __builtin_amdgcn_mfma_f32_16x16x32_bf16(a[mf], b[nf], acc[mf][nf], 0, 0, 0);
    }
  }
  float* outp = qp + (size_t)ks * 8192 * 256;
  #pragma unroll
  for (int mf = 0; mf < 2; mf++) {
    int row = row0 + mf * 16 + (lane >> 4) * 4;
    #pragma unroll
    for (int nf = 0; nf < 4; nf++) {
      int col = w * 64 + nf * 16 + (lane & 15);
      #pragma unroll
      for (int j = 0; j < 4; j++) outp[(size_t)(row + j) * 256 + col] = acc[mf][nf][j];
    }
  }
}

// ============================ K2: scores + wave-parallel top8 + PV gather ============================
// 512 blocks x 16 rows. Phase 1: Q=qp0+qp1 -> bf16 LDS. Phase 2: MFMA scores
// -> Ss (stride 260 f32, per-row reads contiguous). Phase 3: one WAVE per row:
// pack (ordered-score|255-idx) u32, 8x {max4 + 6-step shfl_xor butterfly max,
// owner masks winner}; all lanes decode winners redundantly (no LDS, no
// divergence), softmax + gate, coalesced f32x4 PV gather, gelu -> D bf16.
#define QSTR 264   // ushort stride
#define SSTR 260   // f32 stride: 1040B row -> 16B aligned, contiguous reads
__global__ __launch_bounds__(256, 4) void k_score(unsigned char* __restrict__ ws) {
  const float* qp = (const float*)(ws + WS_QP);
  const unsigned short* sk = (const unsigned short*)(ws + WS_SK);
  const float* relm = (const float*)(ws + WS_REL);
  const float* PV = (const float*)(ws + WS_PV);
  float* gates = (float*)(ws + WS_GATE);
  unsigned short* D = (unsigned short*)(ws + WS_D);
  __shared__ __align__(16) unsigned short Qs[16 * QSTR];
  __shared__ __align__(16) float Ss[16 * SSTR];
  int t = threadIdx.x, lane = t & 63, w = t >> 6;
  int row0 = blockIdx.x * 16;
  // phase 1: query = qpart0 + qpart1 -> bf16 -> LDS (16 rows x 256 cols)
  #pragma unroll
  for (int i = 0; i < 4; i++) {
    int id = i * 256 + t, r = id >> 6, c4 = id & 63;
    const float* p0 = qp + (size_t)(row0 + r) * 256 + c4 * 4;
    f32x4 a = *(const f32x4*)p0;
    f32x4 b = *(const f32x4*)(p0 + 8192 * 256);
    u16x4 o;
    #pragma unroll
    for (int j = 0; j < 4; j++) o[j] = f2bf(a[j] + b[j]);
    *(u16x4*)&Qs[r * QSTR + c4 * 4] = o;
  }
  __syncthreads();
  // phase 2: scores[16][256] = Q @ sk^T / 16 + rel_mask
  {
    f32x4 acc[4] = {};
    for (int ksb = 0; ksb < 8; ksb++) {
      int ck = lane >> 4;
      bf16x8 a = as_bf16(*(const u16x8*)&Qs[(lane & 15) * QSTR + ksb * 32 + ck * 8]);
      #pragma unroll
      for (int nf = 0; nf < 4; nf++) {
        int n = w * 64 + nf * 16 + (lane & 15);
        bf16x8 b = as_bf16(*(const u16x8*)&sk[(size_t)n * 256 + ksb * 32 + ck * 8]);
        acc[nf] = __builtin_amdgcn_mfma_f32_16x16x32_bf16(a, b, acc[nf], 0, 0, 0);
      }
    }
    #pragma unroll
    for (int nf = 0; nf < 4; nf++) {
      int n = w * 64 + nf * 16 + (lane & 15);
      float rm = relm[n];
      int rr = (lane >> 4) * 4;
      #pragma unroll
      for (int j = 0; j < 4; j++) Ss[(rr + j) * SSTR + n] = acc[nf][j] * 0.0625f + rm;
    }
  }
  __syncthreads();
  // phase 3: wave w handles rows w*4 .. w*4+3
  for (int rr = 0; rr < 4; rr++) {
    int row = w * 4 + rr;
    f32x4 sv4 = *(const f32x4*)&Ss[row * SSTR + lane * 4];
    unsigned int key[4];
    #pragma unroll
    for (int j = 0; j < 4; j++) {
      unsigned int u = __builtin_bit_cast(unsigned int, sv4[j]);
      unsigned int os = (u & 0x80000000u) ? ~u : (u | 0x80000000u);
      key[j] = (os & 0xFFFFFF00u) | (unsigned int)(255 - (lane * 4 + j));
    }
    unsigned int win[8];
    #pragma unroll
    for (int e = 0; e < 8; e++) {
      unsigned int m01 = key[0] > key[1] ? key[0] : key[1];
      unsigned int m23 = key[2] > key[3] ? key[2] : key[3];
      unsigned int m = m01 > m23 ? m01 : m23;
      #pragma unroll
      for (int d = 1; d < 64; d <<= 1) {
        unsigned int o = (unsigned int)__shfl_xor((int)m, d, 64);
        m = o > m ? o : m;
      }
      win[e] = m;
      #pragma unroll
      for (int j = 0; j < 4; j++) if (key[j] == m) key[j] = 0u;
    }
    // decode (all lanes redundantly)
    float s8[8]; int i8[8];
    #pragma unroll
    for (int e = 0; e < 8; e++) {
      i8[e] = 255 - (int)(win[e] & 0xFFu);
      unsigned int os = win[e] & 0xFFFFFF00u;
      unsigned int u = (os & 0x80000000u) ? (os ^ 0x80000000u) : ~os;
      s8[e] = __builtin_bit_cast(float, u);
    }
    float m0 = s8[0], sum = 0.f, we[8];
    #pragma unroll
    for (int e = 0; e < 8; e++) { we[e] = expf(s8[e] - m0); sum += we[e]; }
    float inv = 1.f / sum;
    // PV gather: lane l owns cols 4l..4l+3 (f32x4, contiguous 1KB per slot)
    f32x4 accv = {0.f, 0.f, 0.f, 0.f};
    #pragma unroll
    for (int e = 0; e < 8; e++) {
      float wk = we[e] * inv;
      f32x4 p = *(const f32x4*)(PV + (size_t)i8[e] * 256 + lane * 4);
      #pragma unroll
      for (int j = 0; j < 4; j++) accv[j] += wk * p[j];
    }
    u16x4 o;
    #pragma unroll
    for (int j = 0; j < 4; j++) o[j] = f2bf(gelu_tanh(accv[j]));
    *(u16x4*)&D[(size_t)(row0 + row) * 256 + lane * 4] = o;
    if (lane == 0) gates[row0 + row] = 1.f / (1.f + expf(-m0));
  }
}

// ============================ K3: up-GEMM + epilogue ============================
// out[r,h] = primary[r,h] + gate[r] * (D[r,:] @ vup[h,:])   K=256
// R7 was latency/TLP-bound (occupancy 21%, 1.7 blocks/CU effective).  Now:
// BM=64 x BN=128 tiles -> 2048 blocks (128 row x 16 col, XCD swizzle),
// acc[2][4]=32 regs, LDS 24.6KB -> 4 blocks/CU at launch_bounds(256,4) with
// no spill (32 acc + 32 pref + temps < 128).  Per-block critical path halves;
// 8 blocks/CU queued give cross-block overlap of the stage-load latency.
// primary prefetch: pref[2][4] double buffer per 32-row epilogue chunk.
union KOutLds {
  unsigned short AB[12288];        // As = AB[0..4095] (64x64), Bs = AB+4096 (128x64)
  float stage[32 * 132];           // 16.9 KB, inside 24.6 KB footprint
};
__global__ __launch_bounds__(256, 4) void k_out(const float* __restrict__ primary,
                                                float* __restrict__ out,
                                                unsigned char* __restrict__ ws) {
  const unsigned short* D = (const unsigned short*)(ws + WS_D);
  const unsigned short* vup = (const unsigned short*)(ws + WS_VUP);
  const float* gates = (const float*)(ws + WS_GATE);
  __shared__ __align__(16) KOutLds u;
  __shared__ float gate_s[64];
  unsigned short* As = u.AB;
  unsigned short* Bs = u.AB + 4096;
  int t = threadIdx.x, lane = t & 63, w = t >> 6;
  int bid = blockIdx.x;
  int L = (bid & 7) * 256 + (bid >> 3);   // bijective: 2048 % 8 == 0
  int rt = L >> 4, ct = L & 15;           // rt in [0,128), ct in [0,16)
  int wm = w >> 1, wn = w & 1;            // wave tile: 32 rows x 64 cols
  // per-chunk primary prefetch: thread t covers rows {chunk*32 + i*8 + (t>>5)},
  // cols ct*128 + (t&31)*4 .. +3
  const float* pbase = primary + (size_t)(rt * 64 + (t >> 5)) * 2048 + ct * 128 + (t & 31) * 4;
  f32x4 pref[2][4];
  #pragma unroll
  for (int i = 0; i < 4; i++)   // chunk 0 -> pref[0], hides under whole GEMM
    pref[0][i] = *(const f32x4*)(pbase + (size_t)(i * 8) * 2048);
  if (t < 64) gate_s[t] = gates[rt * 64 + t];
  f32x4 acc[2][4] = {};
  for (int k0 = 0; k0 < 256; k0 += 64) {
    __syncthreads();
    #pragma unroll
    for (int i = 0; i < 2; i++) {   // A: D tile 64x64
      int id = i * 256 + t, r = id >> 3, c = id & 7;
      *(u16x8*)&As[r * 64 + ((c ^ (r & 7)) * 8)] =
          *(const u16x8*)&D[(size_t)(rt * 64 + r) * 256 + k0 + c * 8];
    }
    #pragma unroll
    for (int i = 0; i < 4; i++) {   // B: vup tile 128x64
      int id = i * 256 + t, r = id >> 3, c = id & 7;
      *(u16x8*)&Bs[r * 64 + ((c ^ (r & 7)) * 8)] =
          *(const u16x8*)&vup[(size_t)(ct * 128 + r) * 256 + k0 + c * 8];
    }
    __syncthreads();
    #pragma unroll
    for (int kk = 0; kk < 2; kk++) {
      int ck = kk * 4 + (lane >> 4);
      bf16x8 a[2], b[4];
      #pragma unroll
      for (int mf = 0; mf < 2; mf++) {
        int ar = wm * 32 + mf * 16 + (lane & 15);
        a[mf] = as_bf16(*(const u16x8*)&As[ar * 64 + ((ck ^ (ar & 7)) * 8)]);
      }
      #pragma unroll
      for (int nf = 0; nf < 4; nf++) {
        int br = wn * 64 + nf * 16 + (lane & 15);
        b[nf] = as_bf16(*(const u16x8*)&Bs[br * 64 + ((ck ^ (br & 7)) * 8)]);
      }
      #pragma unroll
      for (int mf = 0; mf < 2; mf++)
        #pragma unroll
        for (int nf = 0; nf < 4; nf++)
          acc[mf][nf] = __builtin_amdgcn_mfma_f32_16x16x32_bf16(a[mf], b[nf], acc[mf][nf], 0, 0, 0);
    }
  }
  // ---- coalesced epilogue: 2 chunks of 32 rows x 128 cols ----
  #pragma unroll
  for (int c = 0; c < 2; c++) {
    __syncthreads();   // prior readers of LDS done
    if (wm == c) {     // the 2 waves owning these 32 rows stage their acc
      #pragma unroll
      for (int mf = 0; mf < 2; mf++) {
        #pragma unroll
        for (int nf = 0; nf < 4; nf++) {
          int col = wn * 64 + nf * 16 + (lane & 15);
          #pragma unroll
          for (int j = 0; j < 4; j++) {
            int r = mf * 16 + (lane >> 4) * 4 + j;
            u.stage[r * 132 + col] = acc[mf][nf][j];
          }
        }
      }
    }
    if (c == 0) {  // prefetch chunk 1's primary (hidden under stage+store)
      #pragma unroll
      for (int i = 0; i < 4; i++)
        pref[1][i] = *(const f32x4*)(pbase + (size_t)(32 + i * 8) * 2048);
    }
    __syncthreads();
    #pragma unroll
    for (int i = 0; i < 4; i++) {
      int idx = i * 256 + t, r = idx >> 5, c4 = idx & 31;
      int row = rt * 64 + c * 32 + r;
      size_t o = (size_t)row * 2048 + ct * 128 + c4 * 4;
      f32x4 p = pref[c][i];
      f32x4 s = *(const f32x4*)&u.stage[r * 132 + c4 * 4];
      float g = gate_s[c * 32 + r];
      f32x4 ov;
      #pragma unroll
      for (int j = 0; j < 4; j++) ov[j] = p[j] + g * s[j];
      *(f32x4*)(out + o) = ov;
    }
  }
}

// ============================ launch ============================
extern "C" void kernel_launch(void* const* d_in, const int* in_sizes, int n_in,
                              void* d_out, int out_size, void* d_ws, size_t ws_size,
                              hipStream_t stream) {
  const float* hs      = (const float*)d_in[0];
  const float* primary = (const float*)d_in[1];
  const float* qw      = (const float*)d_in[2];
  const float* sk      = (const float*)d_in[3];
  const float* sv      = (const float*)d_in[4];
  const float* rel     = (const float*)d_in[5];
  const float* vdw     = (const float*)d_in[6];
  const float* vup     = (const float*)d_in[7];
  unsigned char* ws = (unsigned char*)d_ws;
  float* out = (float*)d_out;

  k_prep<<<dim3(256), dim3(256), 0, stream>>>(qw, sk, sv, vdw, vup, rel, ws);
  k_pv<<<dim3(64), dim3(256), 0, stream>>>(ws);
  k_query<<<dim3(512), dim3(256), 0, stream>>>(hs, ws);
  k_score<<<dim3(512), dim3(256), 0, stream>>>(ws);
  k_out<<<dim3(2048), dim3(256), 0, stream>>>(primary, out, ws);
}

// Round 9
// 94.359 us; speedup vs baseline: 1.3181x; 1.0078x over previous
//
#include <hip/hip_runtime.h>
#include <stdint.h>

// ============================ problem dims ============================
// hidden_states [4,2048,2048] f32, rows R=8192, H=2048, BD=N=VBD=256, top-8
// out = primary + sigmoid(top1) * gelu_lowrank(softmax_top8 @ gathered vals)
// Key restructure: down-proj is linear -> precompute PV = slot_values @ Wd^T
// (256x256) and gather from PV instead of materializing aux[8192][2048].

typedef float f32x4 __attribute__((ext_vector_type(4)));
typedef unsigned short u16x8 __attribute__((ext_vector_type(8)));
typedef unsigned short u16x4 __attribute__((ext_vector_type(4)));
typedef __bf16 bf16x8 __attribute__((ext_vector_type(8)));

// ============================ ws layout (bytes) ============================
#define WS_QW    0u          // u16 [256*2048]  q_proj_w bf16
#define WS_SK    1048576u    // u16 [256*256]   slot_keys bf16
#define WS_SV    1179648u    // u16 [256*2048]  slot_values bf16
#define WS_VDW   2228224u    // u16 [256*2048]  value_down_w bf16
#define WS_VUP   3276800u    // u16 [2048*256]  value_up_w bf16
#define WS_REL   4325376u    // f32 [256]       log(reliability)
#define WS_PV    4326400u    // f32 [256*256]   slot_values @ Wd^T
#define WS_GATE  4588544u    // f32 [8192]      sigmoid(top1)
#define WS_QP    4621312u    // f32 [2][8192][256] query split-K partials
#define WS_D     21398528u   // u16 [8192*256]  gelu(down) bf16
// total ~24.4 MB

static __device__ __forceinline__ unsigned short f2bf(float f) {
  union { float f; unsigned int u; } v; v.f = f;
  unsigned int r = v.u + 0x7FFFu + ((v.u >> 16) & 1u);
  return (unsigned short)(r >> 16);
}
static __device__ __forceinline__ bf16x8 as_bf16(u16x8 v) {
  return __builtin_bit_cast(bf16x8, v);
}
static __device__ __forceinline__ float gelu_tanh(float x) {
  float u = 0.7978845608028654f * (x + 0.044715f * x * x * x);
  return 0.5f * x * (1.0f + tanhf(u));
}

// ============================ K0: convert weights ============================
__global__ void k_prep(const float* __restrict__ qw, const float* __restrict__ sk,
                       const float* __restrict__ sv, const float* __restrict__ vdw,
                       const float* __restrict__ vup, const float* __restrict__ rel,
                       unsigned char* __restrict__ ws) {
  unsigned short* o_qw  = (unsigned short*)(ws + WS_QW);
  unsigned short* o_sk  = (unsigned short*)(ws + WS_SK);
  unsigned short* o_sv  = (unsigned short*)(ws + WS_SV);
  unsigned short* o_vdw = (unsigned short*)(ws + WS_VDW);
  unsigned short* o_vup = (unsigned short*)(ws + WS_VUP);
  float* o_rel = (float*)(ws + WS_REL);
  int tid = blockIdx.x * blockDim.x + threadIdx.x;
  int stride = gridDim.x * blockDim.x;
  for (int g = tid; g < 540736; g += stride) {
    const float* src; unsigned short* dst; int i;
    if      (g < 131072) { src = qw;  dst = o_qw;  i = g; }
    else if (g < 147456) { src = sk;  dst = o_sk;  i = g - 131072; }
    else if (g < 278528) { src = sv;  dst = o_sv;  i = g - 147456; }
    else if (g < 409600) { src = vdw; dst = o_vdw; i = g - 278528; }
    else if (g < 540672) { src = vup; dst = o_vup; i = g - 409600; }
    else {
      int i4 = (g - 540672) * 4;
      #pragma unroll
      for (int j = 0; j < 4; j++) o_rel[i4 + j] = logf(fmaxf(rel[i4 + j], 1e-10f));
      continue;
    }
    f32x4 v = *(const f32x4*)(src + (size_t)i * 4);
    u16x4 o;
    #pragma unroll
    for (int j = 0; j < 4; j++) o[j] = f2bf(v[j]);
    *(u16x4*)(dst + (size_t)i * 4) = o;
  }
}

// ============================ K_PV: PV = sv @ vdw^T ============================
// 64 blocks, each a 32x32 tile over K=2048. 4 waves, one 16x16 frag each.
__global__ __launch_bounds__(256, 2) void k_pv(unsigned char* __restrict__ ws) {
  const unsigned short* sv  = (const unsigned short*)(ws + WS_SV);
  const unsigned short* vdw = (const unsigned short*)(ws + WS_VDW);
  float* PV = (float*)(ws + WS_PV);
  __shared__ __align__(16) unsigned short As[32 * 64];
  __shared__ __align__(16) unsigned short Bs[32 * 64];
  int t = threadIdx.x, lane = t & 63, w = t >> 6;
  int nt = blockIdx.x >> 3, vt = blockIdx.x & 7;
  int mf = w >> 1, nf = w & 1;
  f32x4 acc = {0.f, 0.f, 0.f, 0.f};
  int r = t >> 3, c = t & 7;
  int sw8 = (c ^ (r & 7)) * 8;
  for (int k0 = 0; k0 < 2048; k0 += 64) {
    __syncthreads();
    *(u16x8*)&As[r * 64 + sw8] = *(const u16x8*)&sv[(size_t)(nt * 32 + r) * 2048 + k0 + c * 8];
    *(u16x8*)&Bs[r * 64 + sw8] = *(const u16x8*)&vdw[(size_t)(vt * 32 + r) * 2048 + k0 + c * 8];
    __syncthreads();
    #pragma unroll
    for (int kk = 0; kk < 2; kk++) {
      int ck = kk * 4 + (lane >> 4);
      int ar = mf * 16 + (lane & 15);
      int br = nf * 16 + (lane & 15);
      bf16x8 a = as_bf16(*(const u16x8*)&As[ar * 64 + ((ck ^ (ar & 7)) * 8)]);
      bf16x8 b = as_bf16(*(const u16x8*)&Bs[br * 64 + ((ck ^ (br & 7)) * 8)]);
      acc = __builtin_amdgcn_mfma_f32_16x16x32_bf16(a, b, acc, 0, 0, 0);
    }
  }
  int row = nt * 32 + mf * 16 + (lane >> 4) * 4;
  int col = vt * 32 + nf * 16 + (lane & 15);
  #pragma unroll
  for (int j = 0; j < 4; j++) PV[(row + j) * 256 + col] = acc[j];
}

// ============================ K1: query GEMM (split-K=2, pipelined) ============================
// qpart[ks][r][d] = hs[r, ks*1024 : +1024] @ qw^T.  BM=32, BN=256(all of BD).
// 512 blocks (256 row tiles x 2 k-slices) -> 4 blocks/CU.  Register-prefetch
// pipeline: issue tile t+1's global loads before the MFMA phase.
__global__ __launch_bounds__(256, 4) void k_query(const float* __restrict__ hs,
                                                  unsigned char* __restrict__ ws) {
  const unsigned short* qw = (const unsigned short*)(ws + WS_QW);
  float* qp = (float*)(ws + WS_QP);
  __shared__ __align__(16) unsigned short As[32 * 64];    // 4 KB
  __shared__ __align__(16) unsigned short Bs[256 * 64];   // 32 KB
  int t = threadIdx.x, lane = t & 63, w = t >> 6;
  int rt = blockIdx.x >> 1, ks = blockIdx.x & 1;
  int row0 = rt * 32, kbase = ks * 1024;
  f32x4 acc[2][4] = {};
  int sr = t >> 3, sc = t & 7;   // staging coords: 32 rows x 8 chunks of 8
  const float* aptr = hs + (size_t)(row0 + sr) * 2048 + kbase + sc * 8;
  const unsigned short* bptr = qw + (size_t)sr * 2048 + kbase + sc * 8;
  f32x4 pa0, pa1;
  u16x8 pb0, pb1, pb2, pb3, pb4, pb5, pb6, pb7;
  // prologue: tile 0 -> regs
  pa0 = *(const f32x4*)(aptr);
  pa1 = *(const f32x4*)(aptr + 4);
  pb0 = *(const u16x8*)(bptr + (size_t)0 * 32 * 2048);
  pb1 = *(const u16x8*)(bptr + (size_t)1 * 32 * 2048);
  pb2 = *(const u16x8*)(bptr + (size_t)2 * 32 * 2048);
  pb3 = *(const u16x8*)(bptr + (size_t)3 * 32 * 2048);
  pb4 = *(const u16x8*)(bptr + (size_t)4 * 32 * 2048);
  pb5 = *(const u16x8*)(bptr + (size_t)5 * 32 * 2048);
  pb6 = *(const u16x8*)(bptr + (size_t)6 * 32 * 2048);
  pb7 = *(const u16x8*)(bptr + (size_t)7 * 32 * 2048);
  for (int kt = 0; kt < 16; kt++) {
    __syncthreads();   // previous tile's LDS readers done
    {  // stage regs -> LDS (A: fp32->bf16)
      u16x8 o;
      #pragma unroll
      for (int j = 0; j < 4; j++) { o[j] = f2bf(pa0[j]); o[4 + j] = f2bf(pa1[j]); }
      *(u16x8*)&As[sr * 64 + ((sc ^ (sr & 7)) * 8)] = o;
      u16x8 pb[8] = {pb0, pb1, pb2, pb3, pb4, pb5, pb6, pb7};
      #pragma unroll
      for (int i = 0; i < 8; i++) {
        int n = i * 32 + sr;
        *(u16x8*)&Bs[n * 64 + ((sc ^ (n & 7)) * 8)] = pb[i];
      }
    }
    __syncthreads();
    if (kt < 15) {  // prefetch tile kt+1 into regs (overlaps MFMA below)
      int off = (kt + 1) * 64;
      pa0 = *(const f32x4*)(aptr + off);
      pa1 = *(const f32x4*)(aptr + off + 4);
      pb0 = *(const u16x8*)(bptr + (size_t)0 * 32 * 2048 + off);
      pb1 = *(const u16x8*)(bptr + (size_t)1 * 32 * 2048 + off);
      pb2 = *(const u16x8*)(bptr + (size_t)2 * 32 * 2048 + off);
      pb3 = *(const u16x8*)(bptr + (size_t)3 * 32 * 2048 + off);
      pb4 = *(const u16x8*)(bptr + (size_t)4 * 32 * 2048 + off);
      pb5 = *(const u16x8*)(bptr + (size_t)5 * 32 * 2048 + off);
      pb6 = *(const u16x8*)(bptr + (size_t)6 * 32 * 2048 + off);
      pb7 = *(const u16x8*)(bptr + (size_t)7 * 32 * 2048 + off);
    }
    #pragma unroll
    for (int kk = 0; kk < 2; kk++) {
      int ck = kk * 4 + (lane >> 4);
      bf16x8 a[2], b[4];
      #pragma unroll
      for (int mf = 0; mf < 2; mf++) {
        int arow = mf * 16 + (lane & 15);
        a[mf] = as_bf16(*(const u16x8*)&As[arow * 64 + ((ck ^ (arow & 7)) * 8)]);
      }
      #pragma unroll
      for (int nf = 0; nf < 4; nf++) {
        int brow = w * 64 + nf * 16 + (lane & 15);
        b[nf] = as_bf16(*(const u16x8*)&Bs[brow * 64 + ((ck ^ (brow & 7)) * 8)]);
      }
      #pragma unroll
      for (int mf = 0; mf < 2; mf++)
        #pragma unroll
        for (int nf = 0; nf < 4; nf++)
          acc[mf][nf] = __builtin_amdgcn_mfma_f32_16x16x32_bf16(a[mf], b[nf], acc[mf][nf], 0, 0, 0);
    }
  }
  float* outp = qp + (size_t)ks * 8192 * 256;
  #pragma unroll
  for (int mf = 0; mf < 2; mf++) {
    int row = row0 + mf * 16 + (lane >> 4) * 4;
    #pragma unroll
    for (int nf = 0; nf < 4; nf++) {
      int col = w * 64 + nf * 16 + (lane & 15);
      #pragma unroll
      for (int j = 0; j < 4; j++) outp[(size_t)(row + j) * 256 + col] = acc[mf][nf][j];
    }
  }
}

// ============================ K2: scores + wave-parallel top8 + PV gather ============================
// 512 blocks x 16 rows. Phase 1: Q=qp0+qp1 -> bf16 LDS. Phase 2: MFMA scores
// -> Ss (stride 260 f32, per-row reads contiguous). Phase 3: one WAVE per row:
// pack (ordered-score|255-idx) u32, 8x {max4 + 6-step shfl_xor butterfly max,
// owner masks winner}; all lanes decode winners redundantly (no LDS, no
// divergence), softmax + gate, coalesced f32x4 PV gather, gelu -> D bf16.
#define QSTR 264   // ushort stride
#define SSTR 260   // f32 stride: 1040B row -> 16B aligned, contiguous reads
__global__ __launch_bounds__(256, 4) void k_score(unsigned char* __restrict__ ws) {
  const float* qp = (const float*)(ws + WS_QP);
  const unsigned short* sk = (const unsigned short*)(ws + WS_SK);
  const float* relm = (const float*)(ws + WS_REL);
  const float* PV = (const float*)(ws + WS_PV);
  float* gates = (float*)(ws + WS_GATE);
  unsigned short* D = (unsigned short*)(ws + WS_D);
  __shared__ __align__(16) unsigned short Qs[16 * QSTR];
  __shared__ __align__(16) float Ss[16 * SSTR];
  int t = threadIdx.x, lane = t & 63, w = t >> 6;
  int row0 = blockIdx.x * 16;
  // phase 1: query = qpart0 + qpart1 -> bf16 -> LDS (16 rows x 256 cols)
  #pragma unroll
  for (int i = 0; i < 4; i++) {
    int id = i * 256 + t, r = id >> 6, c4 = id & 63;
    const float* p0 = qp + (size_t)(row0 + r) * 256 + c4 * 4;
    f32x4 a = *(const f32x4*)p0;
    f32x4 b = *(const f32x4*)(p0 + 8192 * 256);
    u16x4 o;
    #pragma unroll
    for (int j = 0; j < 4; j++) o[j] = f2bf(a[j] + b[j]);
    *(u16x4*)&Qs[r * QSTR + c4 * 4] = o;
  }
  __syncthreads();
  // phase 2: scores[16][256] = Q @ sk^T / 16 + rel_mask
  {
    f32x4 acc[4] = {};
    for (int ksb = 0; ksb < 8; ksb++) {
      int ck = lane >> 4;
      bf16x8 a = as_bf16(*(const u16x8*)&Qs[(lane & 15) * QSTR + ksb * 32 + ck * 8]);
      #pragma unroll
      for (int nf = 0; nf < 4; nf++) {
        int n = w * 64 + nf * 16 + (lane & 15);
        bf16x8 b = as_bf16(*(const u16x8*)&sk[(size_t)n * 256 + ksb * 32 + ck * 8]);
        acc[nf] = __builtin_amdgcn_mfma_f32_16x16x32_bf16(a, b, acc[nf], 0, 0, 0);
      }
    }
    #pragma unroll
    for (int nf = 0; nf < 4; nf++) {
      int n = w * 64 + nf * 16 + (lane & 15);
      float rm = relm[n];
      int rr = (lane >> 4) * 4;
      #pragma unroll
      for (int j = 0; j < 4; j++) Ss[(rr + j) * SSTR + n] = acc[nf][j] * 0.0625f + rm;
    }
  }
  __syncthreads();
  // phase 3: wave w handles rows w*4 .. w*4+3
  for (int rr = 0; rr < 4; rr++) {
    int row = w * 4 + rr;
    f32x4 sv4 = *(const f32x4*)&Ss[row * SSTR + lane * 4];
    unsigned int key[4];
    #pragma unroll
    for (int j = 0; j < 4; j++) {
      unsigned int u = __builtin_bit_cast(unsigned int, sv4[j]);
      unsigned int os = (u & 0x80000000u) ? ~u : (u | 0x80000000u);
      key[j] = (os & 0xFFFFFF00u) | (unsigned int)(255 - (lane * 4 + j));
    }
    unsigned int win[8];
    #pragma unroll
    for (int e = 0; e < 8; e++) {
      unsigned int m01 = key[0] > key[1] ? key[0] : key[1];
      unsigned int m23 = key[2] > key[3] ? key[2] : key[3];
      unsigned int m = m01 > m23 ? m01 : m23;
      #pragma unroll
      for (int d = 1; d < 64; d <<= 1) {
        unsigned int o = (unsigned int)__shfl_xor((int)m, d, 64);
        m = o > m ? o : m;
      }
      win[e] = m;
      #pragma unroll
      for (int j = 0; j < 4; j++) if (key[j] == m) key[j] = 0u;
    }
    // decode (all lanes redundantly)
    float s8[8]; int i8[8];
    #pragma unroll
    for (int e = 0; e < 8; e++) {
      i8[e] = 255 - (int)(win[e] & 0xFFu);
      unsigned int os = win[e] & 0xFFFFFF00u;
      unsigned int u = (os & 0x80000000u) ? (os ^ 0x80000000u) : ~os;
      s8[e] = __builtin_bit_cast(float, u);
    }
    float m0 = s8[0], sum = 0.f, we[8];
    #pragma unroll
    for (int e = 0; e < 8; e++) { we[e] = expf(s8[e] - m0); sum += we[e]; }
    float inv = 1.f / sum;
    // PV gather: lane l owns cols 4l..4l+3 (f32x4, contiguous 1KB per slot)
    f32x4 accv = {0.f, 0.f, 0.f, 0.f};
    #pragma unroll
    for (int e = 0; e < 8; e++) {
      float wk = we[e] * inv;
      f32x4 p = *(const f32x4*)(PV + (size_t)i8[e] * 256 + lane * 4);
      #pragma unroll
      for (int j = 0; j < 4; j++) accv[j] += wk * p[j];
    }
    u16x4 o;
    #pragma unroll
    for (int j = 0; j < 4; j++) o[j] = f2bf(gelu_tanh(accv[j]));
    *(u16x4*)&D[(size_t)(row0 + row) * 256 + lane * 4] = o;
    if (lane == 0) gates[row0 + row] = 1.f / (1.f + expf(-m0));
  }
}

// ============================ K3: up-GEMM + epilogue ============================
// out[r,h] = primary[r,h] + gate[r] * (D[r,:] @ vup[h,:])   K=256
// BM=64 x BN=128, 2048 blocks (128 row x 16 col, XCD swizzle), 4 blocks/CU.
// R8 lesson: K-loop staging loads were exposed (occupancy 31%, 2.3 TB/s).
// Now the K-loop is register-prefetch pipelined exactly like k_query: tile kt
// lives in 6 u16x8 regs, is written to LDS, then tile kt+1's loads issue
// BEFORE the MFMA phase -> 3 of 4 load-stalls hide under MFMA + barrier.
// primary prefetch: pref[2][4] double buffer per 32-row epilogue chunk.
// Reg budget: 32 acc + 32 pref + 24 K-pipe + temps ~= 110 < 128 (256,4 cap).
union KOutLds {
  unsigned short AB[12288];        // As = AB[0..4095] (64x64), Bs = AB+4096 (128x64)
  float stage[32 * 132];           // 16.9 KB, inside 24.6 KB footprint
};
__global__ __launch_bounds__(256, 4) void k_out(const float* __restrict__ primary,
                                                float* __restrict__ out,
                                                unsigned char* __restrict__ ws) {
  const unsigned short* D = (const unsigned short*)(ws + WS_D);
  const unsigned short* vup = (const unsigned short*)(ws + WS_VUP);
  const float* gates = (const float*)(ws + WS_GATE);
  __shared__ __align__(16) KOutLds u;
  __shared__ float gate_s[64];
  unsigned short* As = u.AB;
  unsigned short* Bs = u.AB + 4096;
  int t = threadIdx.x, lane = t & 63, w = t >> 6;
  int bid = blockIdx.x;
  int L = (bid & 7) * 256 + (bid >> 3);   // bijective: 2048 % 8 == 0
  int rt = L >> 4, ct = L & 15;           // rt in [0,128), ct in [0,16)
  int wm = w >> 1, wn = w & 1;            // wave tile: 32 rows x 64 cols
  // primary prefetch: thread t covers rows {chunk*32 + i*8 + (t>>5)}, 4 cols
  const float* pbase = primary + (size_t)(rt * 64 + (t >> 5)) * 2048 + ct * 128 + (t & 31) * 4;
  f32x4 pref[2][4];
  #pragma unroll
  for (int i = 0; i < 4; i++)   // chunk 0 -> pref[0], hides under whole GEMM
    pref[0][i] = *(const f32x4*)(pbase + (size_t)(i * 8) * 2048);
  // K-pipeline staging coords: sr in [0,32), sc in [0,8)
  int sr = t >> 3, sc = t & 7;
  const unsigned short* aptr = D + (size_t)(rt * 64 + sr) * 256 + sc * 8;     // rows sr, sr+32
  const unsigned short* bptr = vup + (size_t)(ct * 128 + sr) * 256 + sc * 8;  // rows sr,+32,+64,+96
  u16x8 pA0, pA1, pB0, pB1, pB2, pB3;
  pA0 = *(const u16x8*)(aptr);
  pA1 = *(const u16x8*)(aptr + 32 * 256);
  pB0 = *(const u16x8*)(bptr);
  pB1 = *(const u16x8*)(bptr + 32 * 256);
  pB2 = *(const u16x8*)(bptr + 64 * 256);
  pB3 = *(const u16x8*)(bptr + 96 * 256);
  if (t < 64) gate_s[t] = gates[rt * 64 + t];
  f32x4 acc[2][4] = {};
  for (int k0 = 0; k0 < 256; k0 += 64) {
    __syncthreads();   // previous tile's LDS readers done
    {  // stage regs -> LDS (swizzled)
      int r0 = sr, r1 = sr + 32, r2 = sr + 64, r3 = sr + 96;
      *(u16x8*)&As[r0 * 64 + ((sc ^ (r0 & 7)) * 8)] = pA0;
      *(u16x8*)&As[r1 * 64 + ((sc ^ (r1 & 7)) * 8)] = pA1;
      *(u16x8*)&Bs[r0 * 64 + ((sc ^ (r0 & 7)) * 8)] = pB0;
      *(u16x8*)&Bs[r1 * 64 + ((sc ^ (r1 & 7)) * 8)] = pB1;
      *(u16x8*)&Bs[r2 * 64 + ((sc ^ (r2 & 7)) * 8)] = pB2;
      *(u16x8*)&Bs[r3 * 64 + ((sc ^ (r3 & 7)) * 8)] = pB3;
    }
    __syncthreads();
    if (k0 < 192) {  // prefetch tile kt+1 into regs (overlaps MFMA below)
      int off = k0 + 64;
      pA0 = *(const u16x8*)(aptr + off);
      pA1 = *(const u16x8*)(aptr + 32 * 256 + off);
      pB0 = *(const u16x8*)(bptr + off);
      pB1 = *(const u16x8*)(bptr + 32 * 256 + off);
      pB2 = *(const u16x8*)(bptr + 64 * 256 + off);
      pB3 = *(const u16x8*)(bptr + 96 * 256 + off);
    }
    #pragma unroll
    for (int kk = 0; kk < 2; kk++) {
      int ck = kk * 4 + (lane >> 4);
      bf16x8 a[2], b[4];
      #pragma unroll
      for (int mf = 0; mf < 2; mf++) {
        int ar = wm * 32 + mf * 16 + (lane & 15);
        a[mf] = as_bf16(*(const u16x8*)&As[ar * 64 + ((ck ^ (ar & 7)) * 8)]);
      }
      #pragma unroll
      for (int nf = 0; nf < 4; nf++) {
        int br = wn * 64 + nf * 16 + (lane & 15);
        b[nf] = as_bf16(*(const u16x8*)&Bs[br * 64 + ((ck ^ (br & 7)) * 8)]);
      }
      #pragma unroll
      for (int mf = 0; mf < 2; mf++)
        #pragma unroll
        for (int nf = 0; nf < 4; nf++)
          acc[mf][nf] = __builtin_amdgcn_mfma_f32_16x16x32_bf16(a[mf], b[nf], acc[mf][nf], 0, 0, 0);
    }
  }
  // ---- coalesced epilogue: 2 chunks of 32 rows x 128 cols ----
  #pragma unroll
  for (int c = 0; c < 2; c++) {
    __syncthreads();   // prior readers of LDS done
    if (wm == c) {     // the 2 waves owning these 32 rows stage their acc
      #pragma unroll
      for (int mf = 0; mf < 2; mf++) {
        #pragma unroll
        for (int nf = 0; nf < 4; nf++) {
          int col = wn * 64 + nf * 16 + (lane & 15);
          #pragma unroll
          for (int j = 0; j < 4; j++) {
            int r = mf * 16 + (lane >> 4) * 4 + j;
            u.stage[r * 132 + col] = acc[mf][nf][j];
          }
        }
      }
    }
    if (c == 0) {  // prefetch chunk 1's primary (hidden under stage+store)
      #pragma unroll
      for (int i = 0; i < 4; i++)
        pref[1][i] = *(const f32x4*)(pbase + (size_t)(32 + i * 8) * 2048);
    }
    __syncthreads();
    #pragma unroll
    for (int i = 0; i < 4; i++) {
      int idx = i * 256 + t, r = idx >> 5, c4 = idx & 31;
      int row = rt * 64 + c * 32 + r;
      size_t o = (size_t)row * 2048 + ct * 128 + c4 * 4;
      f32x4 p = pref[c][i];
      f32x4 s = *(const f32x4*)&u.stage[r * 132 + c4 * 4];
      float g = gate_s[c * 32 + r];
      f32x4 ov;
      #pragma unroll
      for (int j = 0; j < 4; j++) ov[j] = p[j] + g * s[j];
      *(f32x4*)(out + o) = ov;
    }
  }
}

// ============================ launch ============================
extern "C" void kernel_launch(void* const* d_in, const int* in_sizes, int n_in,
                              void* d_out, int out_size, void* d_ws, size_t ws_size,
                              hipStream_t stream) {
  const float* hs      = (const float*)d_in[0];
  const float* primary = (const float*)d_in[1];
  const float* qw      = (const float*)d_in[2];
  const float* sk      = (const float*)d_in[3];
  const float* sv      = (const float*)d_in[4];
  const float* rel     = (const float*)d_in[5];
  const float* vdw     = (const float*)d_in[6];
  const float* vup     = (const float*)d_in[7];
  unsigned char* ws = (unsigned char*)d_ws;
  float* out = (float*)d_out;

  k_prep<<<dim3(256), dim3(256), 0, stream>>>(qw, sk, sv, vdw, vup, rel, ws);
  k_pv<<<dim3(64), dim3(256), 0, stream>>>(ws);
  k_query<<<dim3(512), dim3(256), 0, stream>>>(hs, ws);
  k_score<<<dim3(512), dim3(256), 0, stream>>>(ws);
  k_out<<<dim3(2048), dim3(256), 0, stream>>>(primary, out, ws);
}